// Round 1
// baseline (471.218 us; speedup 1.0000x reference)
//
#include <hip/hip_runtime.h>
#include <cmath>

typedef __attribute__((ext_vector_type(8))) _Float16 half8;
typedef __attribute__((ext_vector_type(4))) _Float16 half4;
typedef __attribute__((ext_vector_type(4))) float f32x4;

__device__ __forceinline__ void glds16(const void* g, void* l) {
  __builtin_amdgcn_global_load_lds(
      (__attribute__((address_space(1))) const void*)g,
      (__attribute__((address_space(3))) void*)l, 16, 0, 0);
}

// ---------------- f32 -> f16 convert (8 elems/thread) ----------------
__global__ __launch_bounds__(256) void k_cvt(const float* __restrict__ in,
                                             _Float16* __restrict__ out) {
  int i = (blockIdx.x * 256 + threadIdx.x) * 8;
  const f32x4* p = (const f32x4*)(in + i);
  f32x4 a = p[0], b = p[1];
  half8 h;
  h[0] = (_Float16)a[0]; h[1] = (_Float16)a[1]; h[2] = (_Float16)a[2]; h[3] = (_Float16)a[3];
  h[4] = (_Float16)b[0]; h[5] = (_Float16)b[1]; h[6] = (_Float16)b[2]; h[7] = (_Float16)b[3];
  *(half8*)(out + i) = h;
}

// ---------------- W [K,N] f32 -> Wt [N,K] f16 (tiled transpose) ----------------
__global__ __launch_bounds__(256) void k_wt(const float* __restrict__ W,
                                            _Float16* __restrict__ Wt, int K, int N) {
  __shared__ float t[32][33];
  int x = threadIdx.x & 31, y4 = (threadIdx.x >> 5) << 2;
  int n0 = blockIdx.x << 5, k0 = blockIdx.y << 5;
#pragma unroll
  for (int r = 0; r < 4; ++r) t[y4 + r][x] = W[(size_t)(k0 + y4 + r) * N + n0 + x];
  __syncthreads();
#pragma unroll
  for (int r = 0; r < 4; ++r) Wt[(size_t)(n0 + y4 + r) * K + k0 + x] = (_Float16)t[x][y4 + r];
}

__global__ void k_biascat(const float* __restrict__ a, const float* __restrict__ b,
                          const float* __restrict__ c, float* __restrict__ o) {
  int i = blockIdx.x * 256 + threadIdx.x;
  const float* s = i < 1024 ? a : (i < 2048 ? b : c);
  o[i] = s[i & 1023];
}

// ---------------- GEMM: C[M,N] = A[M,K] * Bt[N,K]^T (+epilogue) ----------------
// EPI 0: outh = acc+bias          (QKV)
// EPI 1: t = acc+bias+res; outf=t; outh=(f16)t   (O-proj + residual)
// EPI 2: outh = gelu(acc+bias)    (FFN1)
// EPI 3: outf = acc+bias+res      (FFN2 + residual)
template <int EPI>
__global__ __launch_bounds__(256) void k_gemm(
    const _Float16* __restrict__ A, const _Float16* __restrict__ Bt,
    const float* __restrict__ bias, const float* __restrict__ res,
    float* __restrict__ outf, _Float16* __restrict__ outh, int M, int N, int K) {
  __shared__ _Float16 As[128 * 64];
  __shared__ _Float16 Bs[128 * 64];
  const int tid = threadIdx.x;
  const int lane = tid & 63, w = tid >> 6;
  const int wr = w >> 1, wc = w & 1;
  const int l15 = lane & 15, grp = lane >> 4;
  const int m0 = blockIdx.y << 7, n0 = blockIdx.x << 7;

  f32x4 acc[4][4] = {};
  const _Float16* aG = A + (size_t)(m0 + (tid >> 3)) * K + (tid & 7) * 8;
  const _Float16* bG = Bt + (size_t)(n0 + (tid >> 3)) * K + (tid & 7) * 8;
  _Float16* aL = As + w * 512;
  _Float16* bL = Bs + w * 512;
  const int kT = K >> 6;
  for (int kt = 0; kt < kT; ++kt) {
    const int ko = kt * 64;
#pragma unroll
    for (int i = 0; i < 4; ++i) {
      glds16(aG + (size_t)i * 32 * K + ko, aL + i * 2048);
      glds16(bG + (size_t)i * 32 * K + ko, bL + i * 2048);
    }
    __syncthreads();
#pragma unroll
    for (int ks = 0; ks < 2; ++ks) {
      half8 af[4], bf[4];
#pragma unroll
      for (int i = 0; i < 4; ++i)
        af[i] = *(const half8*)&As[(wr * 64 + i * 16 + l15) * 64 + ks * 32 + grp * 8];
#pragma unroll
      for (int j = 0; j < 4; ++j)
        bf[j] = *(const half8*)&Bs[(wc * 64 + j * 16 + l15) * 64 + ks * 32 + grp * 8];
#pragma unroll
      for (int i = 0; i < 4; ++i)
#pragma unroll
        for (int j = 0; j < 4; ++j)
          acc[i][j] = __builtin_amdgcn_mfma_f32_16x16x32_f16(af[i], bf[j], acc[i][j], 0, 0, 0);
    }
    __syncthreads();
  }
  float bcol[4];
#pragma unroll
  for (int j = 0; j < 4; ++j) bcol[j] = bias[n0 + wc * 64 + j * 16 + l15];
#pragma unroll
  for (int i = 0; i < 4; ++i) {
#pragma unroll
    for (int r = 0; r < 4; ++r) {
      const size_t row = m0 + wr * 64 + i * 16 + grp * 4 + r;
#pragma unroll
      for (int j = 0; j < 4; ++j) {
        const int col = n0 + wc * 64 + j * 16 + l15;
        float v = acc[i][j][r] + bcol[j];
        const size_t idx = row * N + col;
        if (EPI == 0) {
          outh[idx] = (_Float16)v;
        } else if (EPI == 1) {
          float t = v + res[idx];
          outf[idx] = t;
          outh[idx] = (_Float16)t;
        } else if (EPI == 2) {
          float g = 0.5f * v * (1.0f + erff(v * 0.70710678118654752f));
          outh[idx] = (_Float16)g;
        } else {
          outf[idx] = v + res[idx];
        }
      }
    }
  }
}

// ---------------- V [s,e] (from qkv) -> Vt [bh, e, s] f16 ----------------
__global__ __launch_bounds__(256) void k_vt(const _Float16* __restrict__ qkv,
                                            _Float16* __restrict__ Vt) {
  __shared__ _Float16 t[64 * 66];  // stride 66 avoids column-read bank conflicts
  const int tid = threadIdx.x;
  const int bh = blockIdx.y, b = bh >> 4, h = bh & 15;
  const int s0 = blockIdx.x << 6;
#pragma unroll
  for (int p = 0; p < 2; ++p) {
    int lin = p * 256 + tid;
    int s = lin >> 3, c8 = lin & 7;
    half8 v = *(const half8*)&qkv[(size_t)(b * 1024 + s0 + s) * 3072 + 2048 + h * 64 + c8 * 8];
    union { half8 h8; unsigned u[4]; } u;
    u.h8 = v;
    unsigned* d = (unsigned*)&t[s * 66 + c8 * 8];
#pragma unroll
    for (int k = 0; k < 4; ++k) d[k] = u.u[k];
  }
  __syncthreads();
#pragma unroll
  for (int p = 0; p < 2; ++p) {
    int lin = p * 256 + tid;
    int e = lin >> 3, c8 = lin & 7;
    half8 v;
#pragma unroll
    for (int j = 0; j < 8; ++j) v[j] = t[(c8 * 8 + j) * 66 + e];
    *(half8*)&Vt[(size_t)(bh * 64 + e) * 1024 + s0 + c8 * 8] = v;
  }
}

// ---------------- flash attention: 4 waves, Q-tile 64, KV-tile 128 ----------------
__global__ __launch_bounds__(256) void k_attn(const _Float16* __restrict__ qkv,
                                              const _Float16* __restrict__ Vt,
                                              _Float16* __restrict__ ctx) {
  __shared__ _Float16 Ks[128 * 64];   // [s][e], XOR-swizzled chunks
  __shared__ _Float16 Vs[64 * 128];   // [e][s], XOR-swizzled chunks
  __shared__ _Float16 Ps[4][16 * 136];
  const int tid = threadIdx.x;
  const int lane = tid & 63, w = tid >> 6;
  const int l15 = lane & 15, grp = lane >> 4;
  const int bh = blockIdx.y, b = bh >> 4, h = bh & 15;
  const int q0 = blockIdx.x << 6;
  const float CSC = 0.125f * 1.44269504088896f;  // scale * log2(e)

  half8 qf[2];
  {
    const _Float16* qp = qkv + (size_t)(b * 1024 + q0 + w * 16 + l15) * 3072 + h * 64 + grp * 8;
    qf[0] = *(const half8*)qp;
    qf[1] = *(const half8*)(qp + 32);
  }
  f32x4 octx[4] = {};
  float mrun = -1e30f, lrun = 0.f;

  for (int kt = 0; kt < 8; ++kt) {
    const int s0 = kt * 128;
#pragma unroll
    for (int i = 0; i < 4; ++i) {
      {
        int srow = i * 32 + (tid >> 3);
        int c8 = (tid & 7) ^ (srow & 7);  // pre-swizzled source
        glds16(qkv + (size_t)(b * 1024 + s0 + srow) * 3072 + 1024 + h * 64 + c8 * 8,
               Ks + w * 512 + i * 2048);
      }
      {
        int erow = i * 16 + (tid >> 4);
        int c16 = (tid & 15) ^ (erow & 7);
        glds16(Vt + (size_t)(bh * 64 + erow) * 1024 + s0 + c16 * 8,
               Vs + w * 512 + i * 2048);
      }
    }
    __syncthreads();
    // S^T = K * Q^T   (D: row=s-in-frag, col=q -> softmax is column-local)
    f32x4 sacc[8] = {};
#pragma unroll
    for (int ks = 0; ks < 2; ++ks)
#pragma unroll
      for (int f = 0; f < 8; ++f) {
        int srow = f * 16 + l15;
        half8 kf = *(const half8*)&Ks[srow * 64 + ((ks * 32 + grp * 8) ^ ((srow & 7) * 8))];
        sacc[f] = __builtin_amdgcn_mfma_f32_16x16x32_f16(kf, qf[ks], sacc[f], 0, 0, 0);
      }
    // online softmax for column q = l15
    float sv[8][4];
    float tmax = -1e30f;
#pragma unroll
    for (int f = 0; f < 8; ++f)
#pragma unroll
      for (int r = 0; r < 4; ++r) {
        float v = sacc[f][r] * CSC;
        sv[f][r] = v;
        tmax = fmaxf(tmax, v);
      }
    tmax = fmaxf(tmax, __shfl_xor(tmax, 16));
    tmax = fmaxf(tmax, __shfl_xor(tmax, 32));
    float mnew = fmaxf(mrun, tmax);
    float corr = exp2f(mrun - mnew);
    float tsum = 0.f;
#pragma unroll
    for (int f = 0; f < 8; ++f)
#pragma unroll
      for (int r = 0; r < 4; ++r) {
        float pv = exp2f(sv[f][r] - mnew);
        sv[f][r] = pv;
        tsum += pv;
      }
    tsum += __shfl_xor(tsum, 16);
    tsum += __shfl_xor(tsum, 32);
    lrun = lrun * corr + tsum;
    mrun = mnew;
#pragma unroll
    for (int r = 0; r < 4; ++r) {
      float cq = __shfl(corr, (lane & 48) + grp * 4 + r);  // corr for q-row grp*4+r
#pragma unroll
      for (int jf = 0; jf < 4; ++jf) octx[jf][r] *= cq;
    }
    // P -> per-wave LDS: Ps[q][s], row stride 136
#pragma unroll
    for (int f = 0; f < 8; ++f) {
      half4 pk;
      pk[0] = (_Float16)sv[f][0]; pk[1] = (_Float16)sv[f][1];
      pk[2] = (_Float16)sv[f][2]; pk[3] = (_Float16)sv[f][3];
      *(half4*)&Ps[w][l15 * 136 + f * 16 + grp * 4] = pk;
    }
    // ctx += P * V
#pragma unroll
    for (int ks2 = 0; ks2 < 4; ++ks2) {
      half8 pa = *(const half8*)&Ps[w][l15 * 136 + ks2 * 32 + grp * 8];
#pragma unroll
      for (int jf = 0; jf < 4; ++jf) {
        int erow = jf * 16 + l15;
        half8 vb = *(const half8*)&Vs[erow * 128 + ((ks2 * 32 + grp * 8) ^ ((erow & 7) * 8))];
        octx[jf] = __builtin_amdgcn_mfma_f32_16x16x32_f16(pa, vb, octx[jf], 0, 0, 0);
      }
    }
    __syncthreads();
  }
#pragma unroll
  for (int r = 0; r < 4; ++r) {
    float lq = __shfl(lrun, (lane & 48) + grp * 4 + r);
    float inv = 1.0f / lq;
    const size_t row = b * 1024 + q0 + w * 16 + grp * 4 + r;
#pragma unroll
    for (int jf = 0; jf < 4; ++jf)
      ctx[row * 1024 + h * 64 + jf * 16 + l15] = (_Float16)(octx[jf][r] * inv);
  }
}

// ---------------- LayerNorm (in-place safe: reads before barrier, writes after) ----------------
__global__ __launch_bounds__(256) void k_ln(const float* xin, const float* __restrict__ gamma,
                                            const float* __restrict__ beta, float* out) {
  __shared__ float red[8];
  const int tid = threadIdx.x;
  const size_t row = blockIdx.x;
  f32x4 v = *(const f32x4*)&xin[row * 1024 + tid * 4];
  float s = v[0] + v[1] + v[2] + v[3];
  float s2 = v[0] * v[0] + v[1] * v[1] + v[2] * v[2] + v[3] * v[3];
#pragma unroll
  for (int o = 32; o >= 1; o >>= 1) {
    s += __shfl_xor(s, o);
    s2 += __shfl_xor(s2, o);
  }
  if ((tid & 63) == 0) { red[tid >> 6] = s; red[4 + (tid >> 6)] = s2; }
  __syncthreads();
  s = red[0] + red[1] + red[2] + red[3];
  s2 = red[4] + red[5] + red[6] + red[7];
  float mu = s * (1.0f / 1024.0f);
  float var = s2 * (1.0f / 1024.0f) - mu * mu;
  float rs = rsqrtf(var + 1e-5f);
  f32x4 g = *(const f32x4*)&gamma[tid * 4];
  f32x4 bt = *(const f32x4*)&beta[tid * 4];
  f32x4 o4;
#pragma unroll
  for (int r = 0; r < 4; ++r) o4[r] = (v[r] - mu) * rs * g[r] + bt[r];
  *(f32x4*)&out[row * 1024 + tid * 4] = o4;
}

extern "C" void kernel_launch(void* const* d_in, const int* in_sizes, int n_in,
                              void* d_out, int out_size, void* d_ws, size_t ws_size,
                              hipStream_t stream) {
  (void)in_sizes; (void)n_in; (void)out_size; (void)ws_size;
  const float* x  = (const float*)d_in[0];
  const float* Wq = (const float*)d_in[1];  const float* bq = (const float*)d_in[2];
  const float* Wk = (const float*)d_in[3];  const float* bk = (const float*)d_in[4];
  const float* Wv = (const float*)d_in[5];  const float* bv = (const float*)d_in[6];
  const float* Wo = (const float*)d_in[7];  const float* bo = (const float*)d_in[8];
  const float* W1 = (const float*)d_in[9];  const float* b1 = (const float*)d_in[10];
  const float* W2 = (const float*)d_in[11]; const float* b2 = (const float*)d_in[12];
  const float* gamma = (const float*)d_in[13];
  const float* beta  = (const float*)d_in[14];
  float* out = (float*)d_out;

  char* p = (char*)d_ws;
  _Float16* xb    = (_Float16*)p;  p += (size_t)16 << 20;   // x f16; reused as ctx
  _Float16* qkv   = (_Float16*)p;                            // 48MB; [qkv|Vt] region reused as h (64MB)
  _Float16* hbuf  = (_Float16*)p;  p += (size_t)48 << 20;
  _Float16* Vt    = (_Float16*)p;  p += (size_t)16 << 20;
  _Float16* Wqkvt = (_Float16*)p;  p += (size_t)3072 * 1024 * 2;
  _Float16* Wot   = (_Float16*)p;  p += (size_t)1024 * 1024 * 2;
  _Float16* W1t   = (_Float16*)p;  p += (size_t)4096 * 1024 * 2;
  _Float16* W2t   = (_Float16*)p;  p += (size_t)4096 * 1024 * 2;
  float*    bqkv  = (float*)p;     p += (size_t)3072 * 4;
  float*    x1    = (float*)p;     p += (size_t)32 << 20;
  _Float16* x1b   = (_Float16*)p;  p += (size_t)16 << 20;
  _Float16* ctx   = xb;

  k_cvt<<<4096, 256, 0, stream>>>(x, xb);
  k_wt<<<dim3(32, 32), 256, 0, stream>>>(Wq, Wqkvt, 1024, 1024);
  k_wt<<<dim3(32, 32), 256, 0, stream>>>(Wk, Wqkvt + 1024 * 1024, 1024, 1024);
  k_wt<<<dim3(32, 32), 256, 0, stream>>>(Wv, Wqkvt + 2048 * 1024, 1024, 1024);
  k_wt<<<dim3(32, 32), 256, 0, stream>>>(Wo, Wot, 1024, 1024);
  k_wt<<<dim3(128, 32), 256, 0, stream>>>(W1, W1t, 1024, 4096);
  k_wt<<<dim3(32, 128), 256, 0, stream>>>(W2, W2t, 4096, 1024);
  k_biascat<<<12, 256, 0, stream>>>(bq, bk, bv, bqkv);

  // QKV: [8192,3072] = xb @ [Wq|Wk|Wv]
  k_gemm<0><<<dim3(24, 64), 256, 0, stream>>>(xb, Wqkvt, bqkv, nullptr, nullptr, qkv,
                                              8192, 3072, 1024);
  k_vt<<<dim3(16, 128), 256, 0, stream>>>(qkv, Vt);
  k_attn<<<dim3(16, 128), 256, 0, stream>>>(qkv, Vt, ctx);
  // x1 = x + ctx@Wo + bo
  k_gemm<1><<<dim3(8, 64), 256, 0, stream>>>(ctx, Wot, bo, x, x1, x1b, 8192, 1024, 1024);
  // h = gelu(x1@W1 + b1)
  k_gemm<2><<<dim3(32, 64), 256, 0, stream>>>(x1b, W1t, b1, nullptr, nullptr, hbuf,
                                              8192, 4096, 1024);
  // x2 = x1 + h@W2 + b2  -> d_out
  k_gemm<3><<<dim3(8, 64), 256, 0, stream>>>(hbuf, W2t, b2, x1, out, nullptr, 8192, 1024, 4096);
  // LayerNorm in-place on d_out
  k_ln<<<8192, 256, 0, stream>>>(out, gamma, beta, out);
}

// Round 2
// 440.558 us; speedup vs baseline: 1.0696x; 1.0696x over previous
//
#include <hip/hip_runtime.h>
#include <cmath>

typedef __attribute__((ext_vector_type(8))) _Float16 half8;
typedef __attribute__((ext_vector_type(4))) _Float16 half4;
typedef __attribute__((ext_vector_type(4))) float f32x4;

__device__ __forceinline__ void glds16(const void* g, void* l) {
  __builtin_amdgcn_global_load_lds(
      (__attribute__((address_space(1))) const void*)g,
      (__attribute__((address_space(3))) void*)l, 16, 0, 0);
}

// ---------------- f32 -> f16 convert (8 elems/thread) ----------------
__global__ __launch_bounds__(256) void k_cvt(const float* __restrict__ in,
                                             _Float16* __restrict__ out) {
  int i = (blockIdx.x * 256 + threadIdx.x) * 8;
  const f32x4* p = (const f32x4*)(in + i);
  f32x4 a = p[0], b = p[1];
  half8 h;
  h[0] = (_Float16)a[0]; h[1] = (_Float16)a[1]; h[2] = (_Float16)a[2]; h[3] = (_Float16)a[3];
  h[4] = (_Float16)b[0]; h[5] = (_Float16)b[1]; h[6] = (_Float16)b[2]; h[7] = (_Float16)b[3];
  *(half8*)(out + i) = h;
}

// ---------------- W [K,N] f32 -> Wt [N,K] f16 (tiled transpose) ----------------
__global__ __launch_bounds__(256) void k_wt(const float* __restrict__ W,
                                            _Float16* __restrict__ Wt, int K, int N) {
  __shared__ float t[32][33];
  int x = threadIdx.x & 31, y4 = (threadIdx.x >> 5) << 2;
  int n0 = blockIdx.x << 5, k0 = blockIdx.y << 5;
#pragma unroll
  for (int r = 0; r < 4; ++r) t[y4 + r][x] = W[(size_t)(k0 + y4 + r) * N + n0 + x];
  __syncthreads();
#pragma unroll
  for (int r = 0; r < 4; ++r) Wt[(size_t)(n0 + y4 + r) * K + k0 + x] = (_Float16)t[x][y4 + r];
}

__global__ void k_biascat(const float* __restrict__ a, const float* __restrict__ b,
                          const float* __restrict__ c, float* __restrict__ o) {
  int i = blockIdx.x * 256 + threadIdx.x;
  const float* s = i < 1024 ? a : (i < 2048 ? b : c);
  o[i] = s[i & 1023];
}

// ================= 8-phase 256-wide GEMM, BK=32, 4-buffer ring =================
// C[M,N] = A[M,K] * Bt[N,K]^T (+epilogue). 512 threads = 8 waves (2M x 4N).
// Per iteration: 4 K-tiles of 32, 8 phases; counted vmcnt (never 0) at odd ends.
// EPI 0: outh = acc+bias; 1: t=acc+bias+res; outf=t, outh=(f16)t;
// EPI 2: outh = gelu(acc+bias); 3: outf = acc+bias+res.
template <int BN, int EPI>
__global__ __launch_bounds__(512, 2) void k_gemm8(
    const _Float16* __restrict__ A, const _Float16* __restrict__ Bt,
    const float* __restrict__ bias, const float* __restrict__ res,
    float* __restrict__ outf, _Float16* __restrict__ outh, int M, int N, int K) {
  constexpr int BM = 256;
  constexpr int MR = 8;            // per-wave M fragments (128 rows / 16)
  constexpr int AH = 4;            // M fragments per phase (C-half)
  constexpr int NR = BN / 64;      // per-wave N fragments
  constexpr int IA = 2;            // glds16 issues per A half-K-tile stage
  constexpr int IB = BN / 128;     // issues per B stage
  constexpr int VMN = 2 * (IA + IB);  // counted vmcnt constant
  constexpr int ABUF = BM * 32, BBUF = BN * 32;
  __shared__ _Float16 lds[4 * (ABUF + BBUF)];
  _Float16* ldsB = lds + 4 * ABUF;

  const int tid = threadIdx.x;
  const int lane = tid & 63;
  const int w = tid >> 6, wr = w >> 2, wc = w & 3;
  const int l15 = lane & 15, grp = lane >> 4;
  const int rc = (grp ^ ((l15 ^ (l15 >> 2)) & 3)) * 8;  // swizzled read chunk (f16)
  const int m0 = blockIdx.y * BM, n0 = blockIdx.x * BN;
  const int q = tid >> 2;
  const int cs = ((tid & 3) ^ ((q ^ (q >> 2)) & 3)) * 8;  // inverse-swizzled src chunk
  const _Float16* aSrc = A + (size_t)(m0 + q) * K + cs;
  const _Float16* bSrc = Bt + (size_t)(n0 + q) * K + cs;
  const int NK = K >> 5;

  f32x4 acc[MR][NR] = {};

#define STAGE_A(SJ, KT)                                                       \
  _Pragma("unroll") for (int si = 0; si < IA; ++si)                           \
      glds16(aSrc + (size_t)(si * 128) * K + (KT) * 32,                       \
             lds + (SJ) * ABUF + si * 4096 + tid * 8);
#define STAGE_B(SJ, KT)                                                       \
  _Pragma("unroll") for (int si = 0; si < IB; ++si)                           \
      glds16(bSrc + (size_t)(si * 128) * K + (KT) * 32,                       \
             ldsB + (SJ) * BBUF + si * 4096 + tid * 8);

#define GPHASE(J, MH, DO_A, SJ, KT)                                           \
  {                                                                           \
    half8 af[AH], bf[NR];                                                     \
    const _Float16* pa = lds + (J) * ABUF + (wr * 128 + (MH) * 64) * 32;      \
    _Pragma("unroll") for (int i = 0; i < AH; ++i)                            \
        af[i] = *(const half8*)&pa[(i * 16 + l15) * 32 + rc];                 \
    const _Float16* pb = ldsB + (J) * BBUF + wc * (BN / 4) * 32;              \
    _Pragma("unroll") for (int n = 0; n < NR; ++n)                            \
        bf[n] = *(const half8*)&pb[(n * 16 + l15) * 32 + rc];                 \
    if (DO_A) { STAGE_A(SJ, KT) } else { STAGE_B(SJ, KT) }                    \
    __builtin_amdgcn_s_barrier();                                             \
    asm volatile("s_waitcnt lgkmcnt(0)" ::: "memory");                        \
    __builtin_amdgcn_sched_barrier(0);                                        \
    __builtin_amdgcn_s_setprio(1);                                            \
    _Pragma("unroll") for (int i = 0; i < AH; ++i)                            \
        _Pragma("unroll") for (int n = 0; n < NR; ++n)                        \
            acc[(MH) * AH + i][n] = __builtin_amdgcn_mfma_f32_16x16x32_f16(   \
                af[i], bf[n], acc[(MH) * AH + i][n], 0, 0, 0);                \
    __builtin_amdgcn_s_setprio(0);                                            \
    if (!(DO_A)) {                                                            \
      if constexpr (VMN == 8) asm volatile("s_waitcnt vmcnt(8)" ::: "memory");\
      else asm volatile("s_waitcnt vmcnt(6)" ::: "memory");                   \
    }                                                                         \
    __builtin_amdgcn_s_barrier();                                             \
  }

  // prologue: K-tiles 0,1,2 -> bufs 0,1,2 ; drain buf0 only (counted)
  STAGE_A(0, 0) STAGE_B(0, 0)
  STAGE_A(1, 1) STAGE_B(1, 1)
  STAGE_A(2, 2) STAGE_B(2, 2)
  if constexpr (VMN == 8) asm volatile("s_waitcnt vmcnt(8)" ::: "memory");
  else asm volatile("s_waitcnt vmcnt(6)" ::: "memory");
  __builtin_amdgcn_s_barrier();

  const int T = K >> 7;  // 4 K-tiles per iteration
#pragma unroll 1
  for (int t = 0; t < T; ++t) {
    const int b4 = 4 * t;
    const int k3 = (b4 + 3 < NK - 1) ? b4 + 3 : NK - 1;
    const int k4 = (b4 + 4 < NK - 1) ? b4 + 4 : NK - 1;
    const int k5 = (b4 + 5 < NK - 1) ? b4 + 5 : NK - 1;
    const int k6 = (b4 + 6 < NK - 1) ? b4 + 6 : NK - 1;
    GPHASE(0, 0, true, 3, k3)
    GPHASE(0, 1, false, 3, k3)
    GPHASE(1, 0, true, 0, k4)
    GPHASE(1, 1, false, 0, k4)
    GPHASE(2, 0, true, 1, k5)
    GPHASE(2, 1, false, 1, k5)
    GPHASE(3, 0, true, 2, k6)
    GPHASE(3, 1, false, 2, k6)
  }
  asm volatile("s_waitcnt vmcnt(0)" ::: "memory");
#undef GPHASE
#undef STAGE_A
#undef STAGE_B

  float bcol[NR];
#pragma unroll
  for (int n = 0; n < NR; ++n) bcol[n] = bias[n0 + wc * (BN / 4) + n * 16 + l15];
#pragma unroll
  for (int m = 0; m < MR; ++m) {
#pragma unroll
    for (int rr = 0; rr < 4; ++rr) {
      const size_t row = m0 + wr * 128 + m * 16 + grp * 4 + rr;
#pragma unroll
      for (int n = 0; n < NR; ++n) {
        const int col = n0 + wc * (BN / 4) + n * 16 + l15;
        float v = acc[m][n][rr] + bcol[n];
        const size_t idx = row * N + col;
        if (EPI == 0) {
          outh[idx] = (_Float16)v;
        } else if (EPI == 1) {
          float t2 = v + res[idx];
          outf[idx] = t2;
          outh[idx] = (_Float16)t2;
        } else if (EPI == 2) {
          float g = 0.5f * v * (1.0f + erff(v * 0.70710678118654752f));
          outh[idx] = (_Float16)g;
        } else {
          outf[idx] = v + res[idx];
        }
      }
    }
  }
}

// ---------------- V [s,e] (from qkv) -> Vt [bh, e, s] f16 ----------------
__global__ __launch_bounds__(256) void k_vt(const _Float16* __restrict__ qkv,
                                            _Float16* __restrict__ Vt) {
  __shared__ _Float16 t[64 * 66];
  const int tid = threadIdx.x;
  const int bh = blockIdx.y, b = bh >> 4, h = bh & 15;
  const int s0 = blockIdx.x << 6;
#pragma unroll
  for (int p = 0; p < 2; ++p) {
    int lin = p * 256 + tid;
    int s = lin >> 3, c8 = lin & 7;
    half8 v = *(const half8*)&qkv[(size_t)(b * 1024 + s0 + s) * 3072 + 2048 + h * 64 + c8 * 8];
    union { half8 h8; unsigned u[4]; } u;
    u.h8 = v;
    unsigned* d = (unsigned*)&t[s * 66 + c8 * 8];
#pragma unroll
    for (int k = 0; k < 4; ++k) d[k] = u.u[k];
  }
  __syncthreads();
#pragma unroll
  for (int p = 0; p < 2; ++p) {
    int lin = p * 256 + tid;
    int e = lin >> 3, c8 = lin & 7;
    half8 v;
#pragma unroll
    for (int j = 0; j < 8; ++j) v[j] = t[(c8 * 8 + j) * 66 + e];
    *(half8*)&Vt[(size_t)(bh * 64 + e) * 1024 + s0 + c8 * 8] = v;
  }
}

// ---------------- flash attention: 4 waves, Q-tile 64, KV-tile 128 ----------------
__global__ __launch_bounds__(256) void k_attn(const _Float16* __restrict__ qkv,
                                              const _Float16* __restrict__ Vt,
                                              _Float16* __restrict__ ctx) {
  __shared__ _Float16 Ks[128 * 64];
  __shared__ _Float16 Vs[64 * 128];
  __shared__ _Float16 Ps[4][16 * 136];
  const int tid = threadIdx.x;
  const int lane = tid & 63, w = tid >> 6;
  const int l15 = lane & 15, grp = lane >> 4;
  const int bh = blockIdx.y, b = bh >> 4, h = bh & 15;
  const int q0 = blockIdx.x << 6;
  const float CSC = 0.125f * 1.44269504088896f;

  half8 qf[2];
  {
    const _Float16* qp = qkv + (size_t)(b * 1024 + q0 + w * 16 + l15) * 3072 + h * 64 + grp * 8;
    qf[0] = *(const half8*)qp;
    qf[1] = *(const half8*)(qp + 32);
  }
  f32x4 octx[4] = {};
  float mrun = -1e30f, lrun = 0.f;

  for (int kt = 0; kt < 8; ++kt) {
    const int s0 = kt * 128;
#pragma unroll
    for (int i = 0; i < 4; ++i) {
      {
        int srow = i * 32 + (tid >> 3);
        int c8 = (tid & 7) ^ (srow & 7);
        glds16(qkv + (size_t)(b * 1024 + s0 + srow) * 3072 + 1024 + h * 64 + c8 * 8,
               Ks + w * 512 + i * 2048);
      }
      {
        int erow = i * 16 + (tid >> 4);
        int c16 = (tid & 15) ^ (erow & 7);
        glds16(Vt + (size_t)(bh * 64 + erow) * 1024 + s0 + c16 * 8,
               Vs + w * 512 + i * 2048);
      }
    }
    __syncthreads();
    f32x4 sacc[8] = {};
#pragma unroll
    for (int ks = 0; ks < 2; ++ks)
#pragma unroll
      for (int f = 0; f < 8; ++f) {
        int srow = f * 16 + l15;
        half8 kf = *(const half8*)&Ks[srow * 64 + ((ks * 32 + grp * 8) ^ ((srow & 7) * 8))];
        sacc[f] = __builtin_amdgcn_mfma_f32_16x16x32_f16(kf, qf[ks], sacc[f], 0, 0, 0);
      }
    float sv[8][4];
    float tmax = -1e30f;
#pragma unroll
    for (int f = 0; f < 8; ++f)
#pragma unroll
      for (int r = 0; r < 4; ++r) {
        float v = sacc[f][r] * CSC;
        sv[f][r] = v;
        tmax = fmaxf(tmax, v);
      }
    tmax = fmaxf(tmax, __shfl_xor(tmax, 16));
    tmax = fmaxf(tmax, __shfl_xor(tmax, 32));
    float mnew = fmaxf(mrun, tmax);
    float corr = exp2f(mrun - mnew);
    float tsum = 0.f;
#pragma unroll
    for (int f = 0; f < 8; ++f)
#pragma unroll
      for (int r = 0; r < 4; ++r) {
        float pv = exp2f(sv[f][r] - mnew);
        sv[f][r] = pv;
        tsum += pv;
      }
    tsum += __shfl_xor(tsum, 16);
    tsum += __shfl_xor(tsum, 32);
    lrun = lrun * corr + tsum;
    mrun = mnew;
#pragma unroll
    for (int r = 0; r < 4; ++r) {
      float cq = __shfl(corr, (lane & 48) + grp * 4 + r);
#pragma unroll
      for (int jf = 0; jf < 4; ++jf) octx[jf][r] *= cq;
    }
#pragma unroll
    for (int f = 0; f < 8; ++f) {
      half4 pk;
      pk[0] = (_Float16)sv[f][0]; pk[1] = (_Float16)sv[f][1];
      pk[2] = (_Float16)sv[f][2]; pk[3] = (_Float16)sv[f][3];
      *(half4*)&Ps[w][l15 * 136 + f * 16 + grp * 4] = pk;
    }
#pragma unroll
    for (int ks2 = 0; ks2 < 4; ++ks2) {
      half8 pa = *(const half8*)&Ps[w][l15 * 136 + ks2 * 32 + grp * 8];
#pragma unroll
      for (int jf = 0; jf < 4; ++jf) {
        int erow = jf * 16 + l15;
        half8 vb = *(const half8*)&Vs[erow * 128 + ((ks2 * 32 + grp * 8) ^ ((erow & 7) * 8))];
        octx[jf] = __builtin_amdgcn_mfma_f32_16x16x32_f16(pa, vb, octx[jf], 0, 0, 0);
      }
    }
    __syncthreads();
  }
#pragma unroll
  for (int r = 0; r < 4; ++r) {
    float lq = __shfl(lrun, (lane & 48) + grp * 4 + r);
    float inv = 1.0f / lq;
    const size_t row = b * 1024 + q0 + w * 16 + grp * 4 + r;
#pragma unroll
    for (int jf = 0; jf < 4; ++jf)
      ctx[row * 1024 + h * 64 + jf * 16 + l15] = (_Float16)(octx[jf][r] * inv);
  }
}

// ---------------- LayerNorm ----------------
__global__ __launch_bounds__(256) void k_ln(const float* xin, const float* __restrict__ gamma,
                                            const float* __restrict__ beta, float* out) {
  __shared__ float red[8];
  const int tid = threadIdx.x;
  const size_t row = blockIdx.x;
  f32x4 v = *(const f32x4*)&xin[row * 1024 + tid * 4];
  float s = v[0] + v[1] + v[2] + v[3];
  float s2 = v[0] * v[0] + v[1] * v[1] + v[2] * v[2] + v[3] * v[3];
#pragma unroll
  for (int o = 32; o >= 1; o >>= 1) {
    s += __shfl_xor(s, o);
    s2 += __shfl_xor(s2, o);
  }
  if ((tid & 63) == 0) { red[tid >> 6] = s; red[4 + (tid >> 6)] = s2; }
  __syncthreads();
  s = red[0] + red[1] + red[2] + red[3];
  s2 = red[4] + red[5] + red[6] + red[7];
  float mu = s * (1.0f / 1024.0f);
  float var = s2 * (1.0f / 1024.0f) - mu * mu;
  float rs = rsqrtf(var + 1e-5f);
  f32x4 g = *(const f32x4*)&gamma[tid * 4];
  f32x4 bt = *(const f32x4*)&beta[tid * 4];
  f32x4 o4;
#pragma unroll
  for (int r = 0; r < 4; ++r) o4[r] = (v[r] - mu) * rs * g[r] + bt[r];
  *(f32x4*)&out[row * 1024 + tid * 4] = o4;
}

extern "C" void kernel_launch(void* const* d_in, const int* in_sizes, int n_in,
                              void* d_out, int out_size, void* d_ws, size_t ws_size,
                              hipStream_t stream) {
  (void)in_sizes; (void)n_in; (void)out_size; (void)ws_size;
  const float* x  = (const float*)d_in[0];
  const float* Wq = (const float*)d_in[1];  const float* bq = (const float*)d_in[2];
  const float* Wk = (const float*)d_in[3];  const float* bk = (const float*)d_in[4];
  const float* Wv = (const float*)d_in[5];  const float* bv = (const float*)d_in[6];
  const float* Wo = (const float*)d_in[7];  const float* bo = (const float*)d_in[8];
  const float* W1 = (const float*)d_in[9];  const float* b1 = (const float*)d_in[10];
  const float* W2 = (const float*)d_in[11]; const float* b2 = (const float*)d_in[12];
  const float* gamma = (const float*)d_in[13];
  const float* beta  = (const float*)d_in[14];
  float* out = (float*)d_out;

  char* p = (char*)d_ws;
  _Float16* xb    = (_Float16*)p;  p += (size_t)16 << 20;   // x f16; reused as ctx
  _Float16* qkv   = (_Float16*)p;                            // [qkv|Vt] reused as h
  _Float16* hbuf  = (_Float16*)p;  p += (size_t)48 << 20;
  _Float16* Vt    = (_Float16*)p;  p += (size_t)16 << 20;
  _Float16* Wqkvt = (_Float16*)p;  p += (size_t)3072 * 1024 * 2;
  _Float16* Wot   = (_Float16*)p;  p += (size_t)1024 * 1024 * 2;
  _Float16* W1t   = (_Float16*)p;  p += (size_t)4096 * 1024 * 2;
  _Float16* W2t   = (_Float16*)p;  p += (size_t)4096 * 1024 * 2;
  float*    bqkv  = (float*)p;     p += (size_t)3072 * 4;
  float*    x1    = (float*)p;     p += (size_t)32 << 20;
  _Float16* x1b   = (_Float16*)p;  p += (size_t)16 << 20;
  _Float16* ctx   = xb;

  k_cvt<<<4096, 256, 0, stream>>>(x, xb);
  k_wt<<<dim3(32, 32), 256, 0, stream>>>(Wq, Wqkvt, 1024, 1024);
  k_wt<<<dim3(32, 32), 256, 0, stream>>>(Wk, Wqkvt + 1024 * 1024, 1024, 1024);
  k_wt<<<dim3(32, 32), 256, 0, stream>>>(Wv, Wqkvt + 2048 * 1024, 1024, 1024);
  k_wt<<<dim3(32, 32), 256, 0, stream>>>(Wo, Wot, 1024, 1024);
  k_wt<<<dim3(128, 32), 256, 0, stream>>>(W1, W1t, 1024, 4096);
  k_wt<<<dim3(32, 128), 256, 0, stream>>>(W2, W2t, 4096, 1024);
  k_biascat<<<12, 256, 0, stream>>>(bq, bk, bv, bqkv);

  // QKV: [8192,3072]
  k_gemm8<256, 0><<<dim3(12, 32), 512, 0, stream>>>(xb, Wqkvt, bqkv, nullptr, nullptr, qkv,
                                                    8192, 3072, 1024);
  k_vt<<<dim3(16, 128), 256, 0, stream>>>(qkv, Vt);
  k_attn<<<dim3(16, 128), 256, 0, stream>>>(qkv, Vt, ctx);
  // x1 = x + ctx@Wo + bo
  k_gemm8<128, 1><<<dim3(8, 32), 512, 0, stream>>>(ctx, Wot, bo, x, x1, x1b, 8192, 1024, 1024);
  // h = gelu(x1@W1 + b1)
  k_gemm8<256, 2><<<dim3(16, 32), 512, 0, stream>>>(x1b, W1t, b1, nullptr, nullptr, hbuf,
                                                    8192, 4096, 1024);
  // x2 = x1 + h@W2 + b2 -> d_out
  k_gemm8<128, 3><<<dim3(8, 32), 512, 0, stream>>>(hbuf, W2t, b2, x1, out, nullptr,
                                                   8192, 1024, 4096);
  k_ln<<<8192, 256, 0, stream>>>(out, gamma, beta, out);
}

// Round 3
// 382.338 us; speedup vs baseline: 1.2325x; 1.1523x over previous
//
#include <hip/hip_runtime.h>
#include <cmath>

typedef __attribute__((ext_vector_type(8))) _Float16 half8;
typedef __attribute__((ext_vector_type(4))) _Float16 half4;
typedef __attribute__((ext_vector_type(4))) float f32x4;

__device__ __forceinline__ void glds16(const void* g, void* l) {
  __builtin_amdgcn_global_load_lds(
      (__attribute__((address_space(1))) const void*)g,
      (__attribute__((address_space(3))) void*)l, 16, 0, 0);
}

// ---------------- f32 -> f16 convert ----------------
__global__ __launch_bounds__(256) void k_cvt(const float* __restrict__ in,
                                             _Float16* __restrict__ out) {
  int i = (blockIdx.x * 256 + threadIdx.x) * 8;
  const f32x4* p = (const f32x4*)(in + i);
  f32x4 a = p[0], b = p[1];
  half8 h;
  h[0] = (_Float16)a[0]; h[1] = (_Float16)a[1]; h[2] = (_Float16)a[2]; h[3] = (_Float16)a[3];
  h[4] = (_Float16)b[0]; h[5] = (_Float16)b[1]; h[6] = (_Float16)b[2]; h[7] = (_Float16)b[3];
  *(half8*)(out + i) = h;
}

// ---------------- W [K,N] f32 -> Wt [N,K] f16 ----------------
__global__ __launch_bounds__(256) void k_wt(const float* __restrict__ W,
                                            _Float16* __restrict__ Wt, int K, int N) {
  __shared__ float t[32][33];
  int x = threadIdx.x & 31, y4 = (threadIdx.x >> 5) << 2;
  int n0 = blockIdx.x << 5, k0 = blockIdx.y << 5;
#pragma unroll
  for (int r = 0; r < 4; ++r) t[y4 + r][x] = W[(size_t)(k0 + y4 + r) * N + n0 + x];
  __syncthreads();
#pragma unroll
  for (int r = 0; r < 4; ++r) Wt[(size_t)(n0 + y4 + r) * K + k0 + x] = (_Float16)t[x][y4 + r];
}

__global__ void k_biascat(const float* __restrict__ a, const float* __restrict__ b,
                          const float* __restrict__ c, float* __restrict__ o) {
  int i = blockIdx.x * 256 + threadIdx.x;
  const float* s = i < 1024 ? a : (i < 2048 ? b : c);
  o[i] = s[i & 1023];
}

// ======== 8-phase GEMM, BK=64, 2 dbuf, quadrant schedule, counted vmcnt ========
// C[M,N] = A[M,K] * Bt[N,K]^T. 512 threads = 8 waves (wr=w>>2 in M, wc=w&3 in N).
// Per-wave C: (BM/2) x 64. Frag interleave: M-frag i at tile row (i*2+wr)*16,
// N-frag n at Bt tile row (n*4+wc)*16 -> M/N halves are contiguous 64/128-row blocks.
// LDS rows are 128B; read swizzle chunk^=(row&7), stage pre-swizzles global source.
// Per K-tile: 4 phases (M0N0)(M0N1)(M1N1)(M1N0); stage kt+1 halves [A0,B0,B1,A1];
// counted vmcnt drains each half exactly one phase before first read. Never 0 in loop.
template <int BM, int EPI>
__global__ __launch_bounds__(512, 2) void k_gemm8(
    const _Float16* __restrict__ A, const _Float16* __restrict__ Bt,
    const float* __restrict__ bias, const float* __restrict__ res,
    float* __restrict__ outf, _Float16* __restrict__ outh, int M, int N, int K) {
  constexpr int MR = BM / 32;      // M frags per wave (8 / 4)
  constexpr int MH2 = MR / 2;      // frags per M-half
  constexpr int AL = BM * 64;      // A buffer elements
  constexpr int BL = 256 * 64;     // B buffer elements
  constexpr int ABYTES = BM * 128;
  constexpr int BBYTES = 256 * 128;
  constexpr int AB2 = 2 * ABYTES;  // byte offset of B region
  __shared__ _Float16 lds[2 * (AL + BL)];
  const char* ldsc = (const char*)lds;

  const int tid = threadIdx.x;
  const int lane = tid & 63;
  const int w = tid >> 6, wr = w >> 2, wc = w & 3;
  const int l15 = lane & 15, grp = lane >> 4;

  // XCD-aware bijective swizzle (all grids here have nwg % 8 == 0)
  const int gx = gridDim.x;
  const int nwg = gx * gridDim.y;
  const int lid = blockIdx.y * gx + blockIdx.x;
  const int wid = (lid & 7) * (nwg >> 3) + (lid >> 3);
  const int m0 = (wid / gx) * BM, n0 = (wid % gx) * 256;

  // swizzled read offsets: logical chunk = ks*4+grp, physical = chunk ^ (l15&7)
  const int m2 = (l15 >> 2) & 1, m01 = l15 & 3;
  const int chunk0 = (m2 << 2) | (grp ^ m01);
  const int aoff0 = wr * 2048 + l15 * 128 + chunk0 * 16;
  const int aoff1 = aoff0 ^ 64;
  const int boff0 = wc * 2048 + l15 * 128 + chunk0 * 16;
  const int boff1 = boff0 ^ 64;

  // staging: thread covers row srow (per 64-row issue), phys chunk tid&7,
  // source chunk pre-swizzled so read-side XOR recovers linear data
  const int srow = tid >> 3;
  const int scs8 = ((tid & 7) ^ (srow & 7)) * 8;
  const int NK = K >> 6;

  f32x4 acc[MR][4] = {};
  half8 af[MH2][2], bf[2][2];

#define STG_A(J, MHH, KN)                                                      \
  _Pragma("unroll") for (int s = 0; s < BM / 128; ++s)                         \
      glds16(A + (size_t)(m0 + (MHH) * (BM / 2) + s * 64 + srow) * K +         \
                 (size_t)(KN)*64 + scs8,                                       \
             lds + (J)*AL + ((MHH) * (BM / 2) + s * 64) * 64 + tid * 8);
#define STG_B(J, NHH, KN)                                                      \
  _Pragma("unroll") for (int s = 0; s < 2; ++s)                                \
      glds16(Bt + (size_t)(n0 + (NHH)*128 + s * 64 + srow) * K +               \
                  (size_t)(KN)*64 + scs8,                                      \
             lds + 2 * AL + (J)*BL + ((NHH)*128 + s * 64) * 64 + tid * 8);

#define VM_P1                                                                  \
  do {                                                                         \
    if constexpr (BM == 256) asm volatile("s_waitcnt vmcnt(4)" ::: "memory");  \
    else asm volatile("s_waitcnt vmcnt(2)" ::: "memory");                      \
  } while (0)
#define VM_P2                                                                  \
  do {                                                                         \
    if constexpr (BM == 256) asm volatile("s_waitcnt vmcnt(4)" ::: "memory");  \
    else asm volatile("s_waitcnt vmcnt(3)" ::: "memory");                      \
  } while (0)
#define VM_P3                                                                  \
  do {                                                                         \
    if constexpr (BM == 256) asm volatile("s_waitcnt vmcnt(4)" ::: "memory");  \
  } while (0)
#define VM_P4 VM_P2

#define PHASE(J, MHQ, NHQ, RA, RB, STGSTMT, VMSTMT)                            \
  {                                                                            \
    if constexpr (RA) {                                                        \
      _Pragma("unroll") for (int i = 0; i < MH2; ++i) {                        \
        af[i][0] = *(const half8*)(ldsc + (J)*ABYTES +                         \
                                   ((MHQ)*MH2 + i) * 4096 + aoff0);            \
        af[i][1] = *(const half8*)(ldsc + (J)*ABYTES +                         \
                                   ((MHQ)*MH2 + i) * 4096 + aoff1);            \
      }                                                                        \
    }                                                                          \
    if constexpr (RB) {                                                        \
      _Pragma("unroll") for (int n = 0; n < 2; ++n) {                          \
        bf[n][0] = *(const half8*)(ldsc + AB2 + (J)*BBYTES +                   \
                                   ((NHQ)*2 + n) * 8192 + boff0);              \
        bf[n][1] = *(const half8*)(ldsc + AB2 + (J)*BBYTES +                   \
                                   ((NHQ)*2 + n) * 8192 + boff1);              \
      }                                                                        \
    }                                                                          \
    STGSTMT;                                                                   \
    __builtin_amdgcn_s_barrier();                                              \
    asm volatile("s_waitcnt lgkmcnt(0)" ::: "memory");                         \
    __builtin_amdgcn_sched_barrier(0);                                         \
    __builtin_amdgcn_s_setprio(1);                                             \
    _Pragma("unroll") for (int ks = 0; ks < 2; ++ks)                           \
        _Pragma("unroll") for (int i = 0; i < MH2; ++i)                        \
            _Pragma("unroll") for (int n = 0; n < 2; ++n)                      \
                acc[(MHQ)*MH2 + i][(NHQ)*2 + n] =                              \
                    __builtin_amdgcn_mfma_f32_16x16x32_f16(                    \
                        af[i][ks], bf[n][ks], acc[(MHQ)*MH2 + i][(NHQ)*2 + n], \
                        0, 0, 0);                                              \
    __builtin_amdgcn_s_setprio(0);                                             \
    VMSTMT;                                                                    \
    __builtin_amdgcn_s_barrier();                                              \
  }

#define KTILE(J, KT)                                                           \
  {                                                                            \
    const int kn_ = ((KT) + 1 < NK) ? (KT) + 1 : (KT);                         \
    PHASE(J, 0, 0, true, true, STG_A(1 - (J), 0, kn_), VM_P1)                  \
    PHASE(J, 0, 1, false, true, STG_B(1 - (J), 0, kn_), VM_P2)                 \
    PHASE(J, 1, 1, true, false, STG_B(1 - (J), 1, kn_), VM_P3)                 \
    PHASE(J, 1, 0, false, true, STG_A(1 - (J), 1, kn_), VM_P4)                 \
  }

  // prologue: stage kt0 halves in queue order [A0, B0, B1, A1]; drain A0,B0
  STG_A(0, 0, 0) STG_B(0, 0, 0) STG_B(0, 1, 0) STG_A(0, 1, 0)
  if constexpr (BM == 256) asm volatile("s_waitcnt vmcnt(4)" ::: "memory");
  else asm volatile("s_waitcnt vmcnt(3)" ::: "memory");
  __builtin_amdgcn_s_barrier();

#pragma unroll 1
  for (int kt = 0; kt < NK; kt += 2) {
    KTILE(0, kt)
    KTILE(1, kt + 1)
  }
  asm volatile("s_waitcnt vmcnt(0)" ::: "memory");
#undef KTILE
#undef PHASE
#undef VM_P1
#undef VM_P2
#undef VM_P3
#undef VM_P4
#undef STG_A
#undef STG_B

  float bcol[4];
#pragma unroll
  for (int n = 0; n < 4; ++n) bcol[n] = bias[n0 + (n * 4 + wc) * 16 + l15];
#pragma unroll
  for (int m = 0; m < MR; ++m) {
#pragma unroll
    for (int rr = 0; rr < 4; ++rr) {
      const size_t row = m0 + (m * 2 + wr) * 16 + grp * 4 + rr;
#pragma unroll
      for (int n = 0; n < 4; ++n) {
        const int col = n0 + (n * 4 + wc) * 16 + l15;
        float v = acc[m][n][rr] + bcol[n];
        const size_t idx = row * N + col;
        if (EPI == 0) {
          outh[idx] = (_Float16)v;
        } else if (EPI == 1) {
          float t2 = v + res[idx];
          outf[idx] = t2;
          outh[idx] = (_Float16)t2;
        } else if (EPI == 2) {
          float g = 0.5f * v * (1.0f + erff(v * 0.70710678118654752f));
          outh[idx] = (_Float16)g;
        } else {
          outf[idx] = v + res[idx];
        }
      }
    }
  }
}

// ---------------- V [s,e] (from qkv) -> Vt [bh, e, s] f16 ----------------
__global__ __launch_bounds__(256) void k_vt(const _Float16* __restrict__ qkv,
                                            _Float16* __restrict__ Vt) {
  __shared__ _Float16 t[64 * 66];
  const int tid = threadIdx.x;
  const int bh = blockIdx.y, b = bh >> 4, h = bh & 15;
  const int s0 = blockIdx.x << 6;
#pragma unroll
  for (int p = 0; p < 2; ++p) {
    int lin = p * 256 + tid;
    int s = lin >> 3, c8 = lin & 7;
    half8 v = *(const half8*)&qkv[(size_t)(b * 1024 + s0 + s) * 3072 + 2048 + h * 64 + c8 * 8];
    union { half8 h8; unsigned u[4]; } u;
    u.h8 = v;
    unsigned* d = (unsigned*)&t[s * 66 + c8 * 8];
#pragma unroll
    for (int k = 0; k < 4; ++k) d[k] = u.u[k];
  }
  __syncthreads();
#pragma unroll
  for (int p = 0; p < 2; ++p) {
    int lin = p * 256 + tid;
    int e = lin >> 3, c8 = lin & 7;
    half8 v;
#pragma unroll
    for (int j = 0; j < 8; ++j) v[j] = t[(c8 * 8 + j) * 66 + e];
    *(half8*)&Vt[(size_t)(bh * 64 + e) * 1024 + s0 + c8 * 8] = v;
  }
}

// ---------------- flash attention: 4 waves, Q-tile 64, KV-tile 128 ----------------
__global__ __launch_bounds__(256) void k_attn(const _Float16* __restrict__ qkv,
                                              const _Float16* __restrict__ Vt,
                                              _Float16* __restrict__ ctx) {
  __shared__ _Float16 Ks[128 * 64];
  __shared__ _Float16 Vs[64 * 128];
  __shared__ _Float16 Ps[4][16 * 136];
  const int tid = threadIdx.x;
  const int lane = tid & 63, w = tid >> 6;
  const int l15 = lane & 15, grp = lane >> 4;
  const int bh = blockIdx.y, b = bh >> 4, h = bh & 15;
  const int q0 = blockIdx.x << 6;
  const float CSC = 0.125f * 1.44269504088896f;

  half8 qf[2];
  {
    const _Float16* qp = qkv + (size_t)(b * 1024 + q0 + w * 16 + l15) * 3072 + h * 64 + grp * 8;
    qf[0] = *(const half8*)qp;
    qf[1] = *(const half8*)(qp + 32);
  }
  f32x4 octx[4] = {};
  float mrun = -1e30f, lrun = 0.f;

  for (int kt = 0; kt < 8; ++kt) {
    const int s0 = kt * 128;
#pragma unroll
    for (int i = 0; i < 4; ++i) {
      {
        int srow = i * 32 + (tid >> 3);
        int c8 = (tid & 7) ^ (srow & 7);
        glds16(qkv + (size_t)(b * 1024 + s0 + srow) * 3072 + 1024 + h * 64 + c8 * 8,
               Ks + w * 512 + i * 2048);
      }
      {
        int erow = i * 16 + (tid >> 4);
        int c16 = (tid & 15) ^ (erow & 7);
        glds16(Vt + (size_t)(bh * 64 + erow) * 1024 + s0 + c16 * 8,
               Vs + w * 512 + i * 2048);
      }
    }
    __syncthreads();
    f32x4 sacc[8] = {};
#pragma unroll
    for (int ks = 0; ks < 2; ++ks)
#pragma unroll
      for (int f = 0; f < 8; ++f) {
        int srow = f * 16 + l15;
        half8 kf = *(const half8*)&Ks[srow * 64 + ((ks * 32 + grp * 8) ^ ((srow & 7) * 8))];
        sacc[f] = __builtin_amdgcn_mfma_f32_16x16x32_f16(kf, qf[ks], sacc[f], 0, 0, 0);
      }
    float sv[8][4];
    float tmax = -1e30f;
#pragma unroll
    for (int f = 0; f < 8; ++f)
#pragma unroll
      for (int r = 0; r < 4; ++r) {
        float v = sacc[f][r] * CSC;
        sv[f][r] = v;
        tmax = fmaxf(tmax, v);
      }
    tmax = fmaxf(tmax, __shfl_xor(tmax, 16));
    tmax = fmaxf(tmax, __shfl_xor(tmax, 32));
    float mnew = fmaxf(mrun, tmax);
    float corr = exp2f(mrun - mnew);
    float tsum = 0.f;
#pragma unroll
    for (int f = 0; f < 8; ++f)
#pragma unroll
      for (int r = 0; r < 4; ++r) {
        float pv = exp2f(sv[f][r] - mnew);
        sv[f][r] = pv;
        tsum += pv;
      }
    tsum += __shfl_xor(tsum, 16);
    tsum += __shfl_xor(tsum, 32);
    lrun = lrun * corr + tsum;
    mrun = mnew;
#pragma unroll
    for (int r = 0; r < 4; ++r) {
      float cq = __shfl(corr, (lane & 48) + grp * 4 + r);
#pragma unroll
      for (int jf = 0; jf < 4; ++jf) octx[jf][r] *= cq;
    }
#pragma unroll
    for (int f = 0; f < 8; ++f) {
      half4 pk;
      pk[0] = (_Float16)sv[f][0]; pk[1] = (_Float16)sv[f][1];
      pk[2] = (_Float16)sv[f][2]; pk[3] = (_Float16)sv[f][3];
      *(half4*)&Ps[w][l15 * 136 + f * 16 + grp * 4] = pk;
    }
#pragma unroll
    for (int ks2 = 0; ks2 < 4; ++ks2) {
      half8 pa = *(const half8*)&Ps[w][l15 * 136 + ks2 * 32 + grp * 8];
#pragma unroll
      for (int jf = 0; jf < 4; ++jf) {
        int erow = jf * 16 + l15;
        half8 vb = *(const half8*)&Vs[erow * 128 + ((ks2 * 32 + grp * 8) ^ ((erow & 7) * 8))];
        octx[jf] = __builtin_amdgcn_mfma_f32_16x16x32_f16(pa, vb, octx[jf], 0, 0, 0);
      }
    }
    __syncthreads();
  }
#pragma unroll
  for (int r = 0; r < 4; ++r) {
    float lq = __shfl(lrun, (lane & 48) + grp * 4 + r);
    float inv = 1.0f / lq;
    const size_t row = b * 1024 + q0 + w * 16 + grp * 4 + r;
#pragma unroll
    for (int jf = 0; jf < 4; ++jf)
      ctx[row * 1024 + h * 64 + jf * 16 + l15] = (_Float16)(octx[jf][r] * inv);
  }
}

// ---------------- LayerNorm ----------------
__global__ __launch_bounds__(256) void k_ln(const float* xin, const float* __restrict__ gamma,
                                            const float* __restrict__ beta, float* out) {
  __shared__ float red[8];
  const int tid = threadIdx.x;
  const size_t row = blockIdx.x;
  f32x4 v = *(const f32x4*)&xin[row * 1024 + tid * 4];
  float s = v[0] + v[1] + v[2] + v[3];
  float s2 = v[0] * v[0] + v[1] * v[1] + v[2] * v[2] + v[3] * v[3];
#pragma unroll
  for (int o = 32; o >= 1; o >>= 1) {
    s += __shfl_xor(s, o);
    s2 += __shfl_xor(s2, o);
  }
  if ((tid & 63) == 0) { red[tid >> 6] = s; red[4 + (tid >> 6)] = s2; }
  __syncthreads();
  s = red[0] + red[1] + red[2] + red[3];
  s2 = red[4] + red[5] + red[6] + red[7];
  float mu = s * (1.0f / 1024.0f);
  float var = s2 * (1.0f / 1024.0f) - mu * mu;
  float rs = rsqrtf(var + 1e-5f);
  f32x4 g = *(const f32x4*)&gamma[tid * 4];
  f32x4 bt = *(const f32x4*)&beta[tid * 4];
  f32x4 o4;
#pragma unroll
  for (int r = 0; r < 4; ++r) o4[r] = (v[r] - mu) * rs * g[r] + bt[r];
  *(f32x4*)&out[row * 1024 + tid * 4] = o4;
}

extern "C" void kernel_launch(void* const* d_in, const int* in_sizes, int n_in,
                              void* d_out, int out_size, void* d_ws, size_t ws_size,
                              hipStream_t stream) {
  (void)in_sizes; (void)n_in; (void)out_size; (void)ws_size;
  const float* x  = (const float*)d_in[0];
  const float* Wq = (const float*)d_in[1];  const float* bq = (const float*)d_in[2];
  const float* Wk = (const float*)d_in[3];  const float* bk = (const float*)d_in[4];
  const float* Wv = (const float*)d_in[5];  const float* bv = (const float*)d_in[6];
  const float* Wo = (const float*)d_in[7];  const float* bo = (const float*)d_in[8];
  const float* W1 = (const float*)d_in[9];  const float* b1 = (const float*)d_in[10];
  const float* W2 = (const float*)d_in[11]; const float* b2 = (const float*)d_in[12];
  const float* gamma = (const float*)d_in[13];
  const float* beta  = (const float*)d_in[14];
  float* out = (float*)d_out;

  char* p = (char*)d_ws;
  _Float16* xb    = (_Float16*)p;  p += (size_t)16 << 20;   // x f16; reused as ctx
  _Float16* qkv   = (_Float16*)p;
  _Float16* hbuf  = (_Float16*)p;  p += (size_t)48 << 20;
  _Float16* Vt    = (_Float16*)p;  p += (size_t)16 << 20;
  _Float16* Wqkvt = (_Float16*)p;  p += (size_t)3072 * 1024 * 2;
  _Float16* Wot   = (_Float16*)p;  p += (size_t)1024 * 1024 * 2;
  _Float16* W1t   = (_Float16*)p;  p += (size_t)4096 * 1024 * 2;
  _Float16* W2t   = (_Float16*)p;  p += (size_t)4096 * 1024 * 2;
  float*    bqkv  = (float*)p;     p += (size_t)3072 * 4;
  float*    x1    = (float*)p;     p += (size_t)32 << 20;
  _Float16* x1b   = (_Float16*)p;  p += (size_t)16 << 20;
  _Float16* ctx   = xb;

  k_cvt<<<4096, 256, 0, stream>>>(x, xb);
  k_wt<<<dim3(32, 32), 256, 0, stream>>>(Wq, Wqkvt, 1024, 1024);
  k_wt<<<dim3(32, 32), 256, 0, stream>>>(Wk, Wqkvt + 1024 * 1024, 1024, 1024);
  k_wt<<<dim3(32, 32), 256, 0, stream>>>(Wv, Wqkvt + 2048 * 1024, 1024, 1024);
  k_wt<<<dim3(32, 32), 256, 0, stream>>>(Wo, Wot, 1024, 1024);
  k_wt<<<dim3(128, 32), 256, 0, stream>>>(W1, W1t, 1024, 4096);
  k_wt<<<dim3(32, 128), 256, 0, stream>>>(W2, W2t, 4096, 1024);
  k_biascat<<<12, 256, 0, stream>>>(bq, bk, bv, bqkv);

  // QKV: [8192,3072], BM=128 -> grid 12x64 = 768 blocks (3 exact rounds)
  k_gemm8<128, 0><<<dim3(12, 64), 512, 0, stream>>>(xb, Wqkvt, bqkv, nullptr, nullptr, qkv,
                                                    8192, 3072, 1024);
  k_vt<<<dim3(16, 128), 256, 0, stream>>>(qkv, Vt);
  k_attn<<<dim3(16, 128), 256, 0, stream>>>(qkv, Vt, ctx);
  // x1 = x + ctx@Wo + bo : BM=128 -> 4x64 = 256 blocks
  k_gemm8<128, 1><<<dim3(4, 64), 512, 0, stream>>>(ctx, Wot, bo, x, x1, x1b, 8192, 1024, 1024);
  // h = gelu(x1@W1 + b1) : BM=256 -> 16x32 = 512 blocks
  k_gemm8<256, 2><<<dim3(16, 32), 512, 0, stream>>>(x1b, W1t, b1, nullptr, nullptr, hbuf,
                                                    8192, 4096, 1024);
  // x2 = x1 + h@W2 + b2 -> d_out : BM=128, K=4096 -> 4x64 = 256 blocks
  k_gemm8<128, 3><<<dim3(4, 64), 512, 0, stream>>>(hbuf, W2t, b2, x1, out, nullptr,
                                                   8192, 1024, 4096);
  k_ln<<<8192, 256, 0, stream>>>(out, gamma, beta, out);
}

// Round 4
// 380.020 us; speedup vs baseline: 1.2400x; 1.0061x over previous
//
#include <hip/hip_runtime.h>
#include <cmath>

typedef __attribute__((ext_vector_type(8))) _Float16 half8;
typedef __attribute__((ext_vector_type(4))) _Float16 half4;
typedef __attribute__((ext_vector_type(4))) float f32x4;

__device__ __forceinline__ void glds16(const void* g, void* l) {
  __builtin_amdgcn_global_load_lds(
      (__attribute__((address_space(1))) const void*)g,
      (__attribute__((address_space(3))) void*)l, 16, 0, 0);
}

// A&S 7.1.26, |err| <= 1.5e-7
__device__ __forceinline__ float fast_erf(float x) {
  float ax = fabsf(x);
  float t = 1.0f / (1.0f + 0.3275911f * ax);
  float y = t * (0.254829592f +
            t * (-0.284496736f +
            t * (1.421413741f +
            t * (-1.453152027f + t * 1.061405429f))));
  float r = 1.0f - y * __expf(-ax * ax);
  return copysignf(r, x);
}

// ---------------- f32 -> f16 convert ----------------
__global__ __launch_bounds__(256) void k_cvt(const float* __restrict__ in,
                                             _Float16* __restrict__ out) {
  int i = (blockIdx.x * 256 + threadIdx.x) * 8;
  const f32x4* p = (const f32x4*)(in + i);
  f32x4 a = p[0], b = p[1];
  half8 h;
  h[0] = (_Float16)a[0]; h[1] = (_Float16)a[1]; h[2] = (_Float16)a[2]; h[3] = (_Float16)a[3];
  h[4] = (_Float16)b[0]; h[5] = (_Float16)b[1]; h[6] = (_Float16)b[2]; h[7] = (_Float16)b[3];
  *(half8*)(out + i) = h;
}

// ---------------- W [K,N] f32 -> Wt [N,K] f16 ----------------
__global__ __launch_bounds__(256) void k_wt(const float* __restrict__ W,
                                            _Float16* __restrict__ Wt, int K, int N) {
  __shared__ float t[32][33];
  int x = threadIdx.x & 31, y4 = (threadIdx.x >> 5) << 2;
  int n0 = blockIdx.x << 5, k0 = blockIdx.y << 5;
#pragma unroll
  for (int r = 0; r < 4; ++r) t[y4 + r][x] = W[(size_t)(k0 + y4 + r) * N + n0 + x];
  __syncthreads();
#pragma unroll
  for (int r = 0; r < 4; ++r) Wt[(size_t)(n0 + y4 + r) * K + k0 + x] = (_Float16)t[x][y4 + r];
}

__global__ void k_biascat(const float* __restrict__ a, const float* __restrict__ b,
                          const float* __restrict__ c, float* __restrict__ o) {
  int i = blockIdx.x * 256 + threadIdx.x;
  const float* s = i < 1024 ? a : (i < 2048 ? b : c);
  o[i] = s[i & 1023];
}

// ======== 8-phase GEMM, BK=64, 2 dbuf, quadrant schedule, deep counted vmcnt ========
// C[M,N] = A[M,K] * Bt[N,K]^T. 512 threads = 8 waves (wr=w>>2 in M, wc=w&3 in N).
// All 4 half-tiles of kt+1 are issued at phase 1 of tile kt (buffer 1-J is free).
// Waits: p1-end vmcnt drains B1,A1 of tile kt (age 4-5 phases);
//        p4-end vmcnt drains A0,B0 of tile kt+1 (age 3 phases). p2,p3: none.
// ds_reads are C++-level so the compiler emits fine-grained lgkmcnt before MFMA.
template <int BM, int EPI>
__global__ __launch_bounds__(512, 2) void k_gemm8(
    const _Float16* __restrict__ A, const _Float16* __restrict__ Bt,
    const float* __restrict__ bias, const float* __restrict__ res,
    float* __restrict__ outf, _Float16* __restrict__ outh, int M, int N, int K) {
  constexpr int MR = BM / 32;      // M frags per wave (8 / 4)
  constexpr int MH2 = MR / 2;      // frags per M-half
  constexpr int AL = BM * 64;      // A buffer elements
  constexpr int BL = 256 * 64;     // B buffer elements
  constexpr int ABYTES = BM * 128;
  constexpr int BBYTES = 256 * 128;
  constexpr int AB2 = 2 * ABYTES;  // byte offset of B region
  __shared__ _Float16 lds[2 * (AL + BL)];
  const char* ldsc = (const char*)lds;

  const int tid = threadIdx.x;
  const int lane = tid & 63;
  const int w = tid >> 6, wr = w >> 2, wc = w & 3;
  const int l15 = lane & 15, grp = lane >> 4;

  // XCD-aware bijective swizzle (all grids here have nwg % 8 == 0)
  const int gx = gridDim.x;
  const int nwg = gx * gridDim.y;
  const int lid = blockIdx.y * gx + blockIdx.x;
  const int wid = (lid & 7) * (nwg >> 3) + (lid >> 3);
  const int m0 = (wid / gx) * BM, n0 = (wid % gx) * 256;

  // swizzled read offsets: physical chunk = logical ^ (l15 & 7)
  const int m2 = (l15 >> 2) & 1, m01 = l15 & 3;
  const int chunk0 = (m2 << 2) | (grp ^ m01);
  const int aoff0 = wr * 2048 + l15 * 128 + chunk0 * 16;
  const int aoff1 = aoff0 ^ 64;
  const int boff0 = wc * 2048 + l15 * 128 + chunk0 * 16;
  const int boff1 = boff0 ^ 64;

  // staging: row srow per 64-row issue, source chunk pre-swizzled (^ row&7)
  const int srow = tid >> 3;
  const int scs8 = ((tid & 7) ^ (srow & 7)) * 8;
  const int NK = K >> 6;

  f32x4 acc[MR][4] = {};
  half8 af[MH2][2], bf[2][2];

#define STG_A(J, MHH, KN)                                                      \
  _Pragma("unroll") for (int s = 0; s < BM / 128; ++s)                         \
      glds16(A + (size_t)(m0 + (MHH) * (BM / 2) + s * 64 + srow) * K +         \
                 (size_t)(KN)*64 + scs8,                                       \
             lds + (J)*AL + ((MHH) * (BM / 2) + s * 64) * 64 + tid * 8);
#define STG_B(J, NHH, KN)                                                      \
  _Pragma("unroll") for (int s = 0; s < 2; ++s)                                \
      glds16(Bt + (size_t)(n0 + (NHH)*128 + s * 64 + srow) * K +               \
                  (size_t)(KN)*64 + scs8,                                      \
             lds + 2 * AL + (J)*BL + ((NHH)*128 + s * 64) * 64 + tid * 8);

// issue all 4 halves of next tile in consumption order [A0, B0, B1, A1]
#define STG_ALL(J, KN)                                                         \
  STG_A(J, 0, KN) STG_B(J, 0, KN) STG_B(J, 1, KN) STG_A(J, 1, KN)

#define VM_A                                                                   \
  do {                                                                         \
    if constexpr (BM == 256) asm volatile("s_waitcnt vmcnt(8)" ::: "memory");  \
    else asm volatile("s_waitcnt vmcnt(6)" ::: "memory");                      \
  } while (0)
#define VM_B                                                                   \
  do {                                                                         \
    if constexpr (BM == 256) asm volatile("s_waitcnt vmcnt(4)" ::: "memory");  \
    else asm volatile("s_waitcnt vmcnt(3)" ::: "memory");                      \
  } while (0)
#define VM_NONE

#define PHASE(J, MHQ, NHQ, RA, RB, STGSTMT, VMSTMT)                            \
  {                                                                            \
    if constexpr (RA) {                                                        \
      _Pragma("unroll") for (int i = 0; i < MH2; ++i) {                        \
        af[i][0] = *(const half8*)(ldsc + (J)*ABYTES +                         \
                                   ((MHQ)*MH2 + i) * 4096 + aoff0);            \
        af[i][1] = *(const half8*)(ldsc + (J)*ABYTES +                         \
                                   ((MHQ)*MH2 + i) * 4096 + aoff1);            \
      }                                                                        \
    }                                                                          \
    if constexpr (RB) {                                                        \
      _Pragma("unroll") for (int n = 0; n < 2; ++n) {                          \
        bf[n][0] = *(const half8*)(ldsc + AB2 + (J)*BBYTES +                   \
                                   ((NHQ)*2 + n) * 8192 + boff0);              \
        bf[n][1] = *(const half8*)(ldsc + AB2 + (J)*BBYTES +                   \
                                   ((NHQ)*2 + n) * 8192 + boff1);              \
      }                                                                        \
    }                                                                          \
    STGSTMT;                                                                   \
    __builtin_amdgcn_s_barrier();                                              \
    __builtin_amdgcn_s_setprio(1);                                             \
    _Pragma("unroll") for (int ks = 0; ks < 2; ++ks)                           \
        _Pragma("unroll") for (int i = 0; i < MH2; ++i)                        \
            _Pragma("unroll") for (int n = 0; n < 2; ++n)                      \
                acc[(MHQ)*MH2 + i][(NHQ)*2 + n] =                              \
                    __builtin_amdgcn_mfma_f32_16x16x32_f16(                    \
                        af[i][ks], bf[n][ks], acc[(MHQ)*MH2 + i][(NHQ)*2 + n], \
                        0, 0, 0);                                              \
    __builtin_amdgcn_s_setprio(0);                                             \
    VMSTMT;                                                                    \
    __builtin_amdgcn_s_barrier();                                              \
  }

#define KTILE(J, KT)                                                           \
  {                                                                            \
    const int kn_ = ((KT) + 1 < NK) ? (KT) + 1 : (KT);                         \
    PHASE(J, 0, 0, true, true, STG_ALL(1 - (J), kn_), VM_A)                    \
    PHASE(J, 0, 1, false, true, , VM_NONE)                                     \
    PHASE(J, 1, 1, true, false, , VM_NONE)                                     \
    PHASE(J, 1, 0, false, true, , VM_B)                                        \
  }

  // prologue: stage tile 0 (order A0,B0,B1,A1); drain A0,B0
  STG_ALL(0, 0)
  VM_B;
  __builtin_amdgcn_s_barrier();

#pragma unroll 1
  for (int kt = 0; kt < NK; kt += 2) {
    KTILE(0, kt)
    KTILE(1, kt + 1)
  }
  asm volatile("s_waitcnt vmcnt(0)" ::: "memory");
#undef KTILE
#undef PHASE
#undef VM_A
#undef VM_B
#undef VM_NONE
#undef STG_ALL
#undef STG_A
#undef STG_B

  float bcol[4];
#pragma unroll
  for (int n = 0; n < 4; ++n) bcol[n] = bias[n0 + (n * 4 + wc) * 16 + l15];
#pragma unroll
  for (int m = 0; m < MR; ++m) {
#pragma unroll
    for (int rr = 0; rr < 4; ++rr) {
      const size_t row = m0 + (m * 2 + wr) * 16 + grp * 4 + rr;
#pragma unroll
      for (int n = 0; n < 4; ++n) {
        const int col = n0 + (n * 4 + wc) * 16 + l15;
        float v = acc[m][n][rr] + bcol[n];
        const size_t idx = row * N + col;
        if (EPI == 0) {
          outh[idx] = (_Float16)v;
        } else if (EPI == 1) {
          float t2 = v + res[idx];
          outf[idx] = t2;
          outh[idx] = (_Float16)t2;
        } else if (EPI == 2) {
          float g = 0.5f * v * (1.0f + fast_erf(v * 0.70710678118654752f));
          outh[idx] = (_Float16)g;
        } else {
          outf[idx] = v + res[idx];
        }
      }
    }
  }
}

// ---------------- V [s,e] (from qkv) -> Vt [bh, e, s] f16 ----------------
__global__ __launch_bounds__(256) void k_vt(const _Float16* __restrict__ qkv,
                                            _Float16* __restrict__ Vt) {
  __shared__ _Float16 t[64 * 66];
  const int tid = threadIdx.x;
  const int bh = blockIdx.y, b = bh >> 4, h = bh & 15;
  const int s0 = blockIdx.x << 6;
#pragma unroll
  for (int p = 0; p < 2; ++p) {
    int lin = p * 256 + tid;
    int s = lin >> 3, c8 = lin & 7;
    half8 v = *(const half8*)&qkv[(size_t)(b * 1024 + s0 + s) * 3072 + 2048 + h * 64 + c8 * 8];
    union { half8 h8; unsigned u[4]; } u;
    u.h8 = v;
    unsigned* d = (unsigned*)&t[s * 66 + c8 * 8];
#pragma unroll
    for (int k = 0; k < 4; ++k) d[k] = u.u[k];
  }
  __syncthreads();
#pragma unroll
  for (int p = 0; p < 2; ++p) {
    int lin = p * 256 + tid;
    int e = lin >> 3, c8 = lin & 7;
    half8 v;
#pragma unroll
    for (int j = 0; j < 8; ++j) v[j] = t[(c8 * 8 + j) * 66 + e];
    *(half8*)&Vt[(size_t)(bh * 64 + e) * 1024 + s0 + c8 * 8] = v;
  }
}

// ---------------- flash attention: 4 waves, Q-tile 64, KV-tile 128 ----------------
__global__ __launch_bounds__(256) void k_attn(const _Float16* __restrict__ qkv,
                                              const _Float16* __restrict__ Vt,
                                              _Float16* __restrict__ ctx) {
  __shared__ _Float16 Ks[128 * 64];
  __shared__ _Float16 Vs[64 * 128];
  __shared__ _Float16 Ps[4][16 * 136];
  const int tid = threadIdx.x;
  const int lane = tid & 63, w = tid >> 6;
  const int l15 = lane & 15, grp = lane >> 4;
  const int bh = blockIdx.y, b = bh >> 4, h = bh & 15;
  const int q0 = blockIdx.x << 6;
  const float CSC = 0.125f * 1.44269504088896f;

  half8 qf[2];
  {
    const _Float16* qp = qkv + (size_t)(b * 1024 + q0 + w * 16 + l15) * 3072 + h * 64 + grp * 8;
    qf[0] = *(const half8*)qp;
    qf[1] = *(const half8*)(qp + 32);
  }
  f32x4 octx[4] = {};
  float mrun = -1e30f, lrun = 0.f;

  for (int kt = 0; kt < 8; ++kt) {
    const int s0 = kt * 128;
#pragma unroll
    for (int i = 0; i < 4; ++i) {
      {
        int srow = i * 32 + (tid >> 3);
        int c8 = (tid & 7) ^ (srow & 7);
        glds16(qkv + (size_t)(b * 1024 + s0 + srow) * 3072 + 1024 + h * 64 + c8 * 8,
               Ks + w * 512 + i * 2048);
      }
      {
        int erow = i * 16 + (tid >> 4);
        int c16 = (tid & 15) ^ (erow & 7);
        glds16(Vt + (size_t)(bh * 64 + erow) * 1024 + s0 + c16 * 8,
               Vs + w * 512 + i * 2048);
      }
    }
    __syncthreads();
    f32x4 sacc[8] = {};
#pragma unroll
    for (int ks = 0; ks < 2; ++ks)
#pragma unroll
      for (int f = 0; f < 8; ++f) {
        int srow = f * 16 + l15;
        half8 kf = *(const half8*)&Ks[srow * 64 + ((ks * 32 + grp * 8) ^ ((srow & 7) * 8))];
        sacc[f] = __builtin_amdgcn_mfma_f32_16x16x32_f16(kf, qf[ks], sacc[f], 0, 0, 0);
      }
    float sv[8][4];
    float tmax = -1e30f;
#pragma unroll
    for (int f = 0; f < 8; ++f)
#pragma unroll
      for (int r = 0; r < 4; ++r) {
        float v = sacc[f][r] * CSC;
        sv[f][r] = v;
        tmax = fmaxf(tmax, v);
      }
    tmax = fmaxf(tmax, __shfl_xor(tmax, 16));
    tmax = fmaxf(tmax, __shfl_xor(tmax, 32));
    float mnew = fmaxf(mrun, tmax);
    float corr = exp2f(mrun - mnew);
    float tsum = 0.f;
#pragma unroll
    for (int f = 0; f < 8; ++f)
#pragma unroll
      for (int r = 0; r < 4; ++r) {
        float pv = exp2f(sv[f][r] - mnew);
        sv[f][r] = pv;
        tsum += pv;
      }
    tsum += __shfl_xor(tsum, 16);
    tsum += __shfl_xor(tsum, 32);
    lrun = lrun * corr + tsum;
    mrun = mnew;
#pragma unroll
    for (int r = 0; r < 4; ++r) {
      float cq = __shfl(corr, (lane & 48) + grp * 4 + r);
#pragma unroll
      for (int jf = 0; jf < 4; ++jf) octx[jf][r] *= cq;
    }
#pragma unroll
    for (int f = 0; f < 8; ++f) {
      half4 pk;
      pk[0] = (_Float16)sv[f][0]; pk[1] = (_Float16)sv[f][1];
      pk[2] = (_Float16)sv[f][2]; pk[3] = (_Float16)sv[f][3];
      *(half4*)&Ps[w][l15 * 136 + f * 16 + grp * 4] = pk;
    }
#pragma unroll
    for (int ks2 = 0; ks2 < 4; ++ks2) {
      half8 pa = *(const half8*)&Ps[w][l15 * 136 + ks2 * 32 + grp * 8];
#pragma unroll
      for (int jf = 0; jf < 4; ++jf) {
        int erow = jf * 16 + l15;
        half8 vb = *(const half8*)&Vs[erow * 128 + ((ks2 * 32 + grp * 8) ^ ((erow & 7) * 8))];
        octx[jf] = __builtin_amdgcn_mfma_f32_16x16x32_f16(pa, vb, octx[jf], 0, 0, 0);
      }
    }
    __syncthreads();
  }
#pragma unroll
  for (int r = 0; r < 4; ++r) {
    float lq = __shfl(lrun, (lane & 48) + grp * 4 + r);
    float inv = 1.0f / lq;
    const size_t row = b * 1024 + q0 + w * 16 + grp * 4 + r;
#pragma unroll
    for (int jf = 0; jf < 4; ++jf)
      ctx[row * 1024 + h * 64 + jf * 16 + l15] = (_Float16)(octx[jf][r] * inv);
  }
}

// ---------------- LayerNorm ----------------
__global__ __launch_bounds__(256) void k_ln(const float* xin, const float* __restrict__ gamma,
                                            const float* __restrict__ beta, float* out) {
  __shared__ float red[8];
  const int tid = threadIdx.x;
  const size_t row = blockIdx.x;
  f32x4 v = *(const f32x4*)&xin[row * 1024 + tid * 4];
  float s = v[0] + v[1] + v[2] + v[3];
  float s2 = v[0] * v[0] + v[1] * v[1] + v[2] * v[2] + v[3] * v[3];
#pragma unroll
  for (int o = 32; o >= 1; o >>= 1) {
    s += __shfl_xor(s, o);
    s2 += __shfl_xor(s2, o);
  }
  if ((tid & 63) == 0) { red[tid >> 6] = s; red[4 + (tid >> 6)] = s2; }
  __syncthreads();
  s = red[0] + red[1] + red[2] + red[3];
  s2 = red[4] + red[5] + red[6] + red[7];
  float mu = s * (1.0f / 1024.0f);
  float var = s2 * (1.0f / 1024.0f) - mu * mu;
  float rs = rsqrtf(var + 1e-5f);
  f32x4 g = *(const f32x4*)&gamma[tid * 4];
  f32x4 bt = *(const f32x4*)&beta[tid * 4];
  f32x4 o4;
#pragma unroll
  for (int r = 0; r < 4; ++r) o4[r] = (v[r] - mu) * rs * g[r] + bt[r];
  *(f32x4*)&out[row * 1024 + tid * 4] = o4;
}

extern "C" void kernel_launch(void* const* d_in, const int* in_sizes, int n_in,
                              void* d_out, int out_size, void* d_ws, size_t ws_size,
                              hipStream_t stream) {
  (void)in_sizes; (void)n_in; (void)out_size; (void)ws_size;
  const float* x  = (const float*)d_in[0];
  const float* Wq = (const float*)d_in[1];  const float* bq = (const float*)d_in[2];
  const float* Wk = (const float*)d_in[3];  const float* bk = (const float*)d_in[4];
  const float* Wv = (const float*)d_in[5];  const float* bv = (const float*)d_in[6];
  const float* Wo = (const float*)d_in[7];  const float* bo = (const float*)d_in[8];
  const float* W1 = (const float*)d_in[9];  const float* b1 = (const float*)d_in[10];
  const float* W2 = (const float*)d_in[11]; const float* b2 = (const float*)d_in[12];
  const float* gamma = (const float*)d_in[13];
  const float* beta  = (const float*)d_in[14];
  float* out = (float*)d_out;

  char* p = (char*)d_ws;
  _Float16* xb    = (_Float16*)p;  p += (size_t)16 << 20;   // x f16; reused as ctx
  _Float16* qkv   = (_Float16*)p;
  _Float16* hbuf  = (_Float16*)p;  p += (size_t)48 << 20;
  _Float16* Vt    = (_Float16*)p;  p += (size_t)16 << 20;
  _Float16* Wqkvt = (_Float16*)p;  p += (size_t)3072 * 1024 * 2;
  _Float16* Wot   = (_Float16*)p;  p += (size_t)1024 * 1024 * 2;
  _Float16* W1t   = (_Float16*)p;  p += (size_t)4096 * 1024 * 2;
  _Float16* W2t   = (_Float16*)p;  p += (size_t)4096 * 1024 * 2;
  float*    bqkv  = (float*)p;     p += (size_t)3072 * 4;
  float*    x1    = (float*)p;     p += (size_t)32 << 20;
  _Float16* x1b   = (_Float16*)p;  p += (size_t)16 << 20;
  _Float16* ctx   = xb;

  k_cvt<<<4096, 256, 0, stream>>>(x, xb);
  k_wt<<<dim3(32, 32), 256, 0, stream>>>(Wq, Wqkvt, 1024, 1024);
  k_wt<<<dim3(32, 32), 256, 0, stream>>>(Wk, Wqkvt + 1024 * 1024, 1024, 1024);
  k_wt<<<dim3(32, 32), 256, 0, stream>>>(Wv, Wqkvt + 2048 * 1024, 1024, 1024);
  k_wt<<<dim3(32, 32), 256, 0, stream>>>(Wo, Wot, 1024, 1024);
  k_wt<<<dim3(128, 32), 256, 0, stream>>>(W1, W1t, 1024, 4096);
  k_wt<<<dim3(32, 128), 256, 0, stream>>>(W2, W2t, 4096, 1024);
  k_biascat<<<12, 256, 0, stream>>>(bq, bk, bv, bqkv);

  // QKV: [8192,3072], BM=128 -> grid 12x64 = 768 blocks (3 exact rounds)
  k_gemm8<128, 0><<<dim3(12, 64), 512, 0, stream>>>(xb, Wqkvt, bqkv, nullptr, nullptr, qkv,
                                                    8192, 3072, 1024);
  k_vt<<<dim3(16, 128), 256, 0, stream>>>(qkv, Vt);
  k_attn<<<dim3(16, 128), 256, 0, stream>>>(qkv, Vt, ctx);
  // x1 = x + ctx@Wo + bo : BM=128 -> 4x64 = 256 blocks
  k_gemm8<128, 1><<<dim3(4, 64), 512, 0, stream>>>(ctx, Wot, bo, x, x1, x1b, 8192, 1024, 1024);
  // h = gelu(x1@W1 + b1) : BM=256 -> 16x32 = 512 blocks
  k_gemm8<256, 2><<<dim3(16, 32), 512, 0, stream>>>(x1b, W1t, b1, nullptr, nullptr, hbuf,
                                                    8192, 4096, 1024);
  // x2 = x1 + h@W2 + b2 -> d_out : BM=128, K=4096 -> 4x64 = 256 blocks
  k_gemm8<128, 3><<<dim3(4, 64), 512, 0, stream>>>(hbuf, W2t, b2, x1, out, nullptr,
                                                   8192, 1024, 4096);
  k_ln<<<8192, 256, 0, stream>>>(out, gamma, beta, out);
}

// Round 5
// 373.009 us; speedup vs baseline: 1.2633x; 1.0188x over previous
//
#include <hip/hip_runtime.h>
#include <cmath>

typedef __attribute__((ext_vector_type(8))) _Float16 half8;
typedef __attribute__((ext_vector_type(4))) _Float16 half4;
typedef __attribute__((ext_vector_type(4))) float f32x4;

__device__ __forceinline__ void glds16(const void* g, void* l) {
  __builtin_amdgcn_global_load_lds(
      (__attribute__((address_space(1))) const void*)g,
      (__attribute__((address_space(3))) void*)l, 16, 0, 0);
}

// A&S 7.1.26, |err| <= 1.5e-7
__device__ __forceinline__ float fast_erf(float x) {
  float ax = fabsf(x);
  float t = 1.0f / (1.0f + 0.3275911f * ax);
  float y = t * (0.254829592f +
            t * (-0.284496736f +
            t * (1.421413741f +
            t * (-1.453152027f + t * 1.061405429f))));
  float r = 1.0f - y * __expf(-ax * ax);
  return copysignf(r, x);
}

// ---------------- f32 -> f16 convert ----------------
__global__ __launch_bounds__(256) void k_cvt(const float* __restrict__ in,
                                             _Float16* __restrict__ out) {
  int i = (blockIdx.x * 256 + threadIdx.x) * 8;
  const f32x4* p = (const f32x4*)(in + i);
  f32x4 a = p[0], b = p[1];
  half8 h;
  h[0] = (_Float16)a[0]; h[1] = (_Float16)a[1]; h[2] = (_Float16)a[2]; h[3] = (_Float16)a[3];
  h[4] = (_Float16)b[0]; h[5] = (_Float16)b[1]; h[6] = (_Float16)b[2]; h[7] = (_Float16)b[3];
  *(half8*)(out + i) = h;
}

// ---------------- W [K,N] f32 -> Wt [N,K] f16 ----------------
__global__ __launch_bounds__(256) void k_wt(const float* __restrict__ W,
                                            _Float16* __restrict__ Wt, int K, int N) {
  __shared__ float t[32][33];
  int x = threadIdx.x & 31, y4 = (threadIdx.x >> 5) << 2;
  int n0 = blockIdx.x << 5, k0 = blockIdx.y << 5;
#pragma unroll
  for (int r = 0; r < 4; ++r) t[y4 + r][x] = W[(size_t)(k0 + y4 + r) * N + n0 + x];
  __syncthreads();
#pragma unroll
  for (int r = 0; r < 4; ++r) Wt[(size_t)(n0 + y4 + r) * K + k0 + x] = (_Float16)t[x][y4 + r];
}

__global__ void k_biascat(const float* __restrict__ a, const float* __restrict__ b,
                          const float* __restrict__ c, float* __restrict__ o) {
  int i = blockIdx.x * 256 + threadIdx.x;
  const float* s = i < 1024 ? a : (i < 2048 ? b : c);
  o[i] = s[i & 1023];
}

// ======== quadrant 8-phase GEMM (FFN1): BM=256,BN=256, BK=64, dbuf, deep vmcnt ========
template <int BM, int EPI>
__global__ __launch_bounds__(512, 2) void k_gemm8(
    const _Float16* __restrict__ A, const _Float16* __restrict__ Bt,
    const float* __restrict__ bias, const float* __restrict__ res,
    float* __restrict__ outf, _Float16* __restrict__ outh, int M, int N, int K) {
  constexpr int MR = BM / 32;
  constexpr int MH2 = MR / 2;
  constexpr int AL = BM * 64;
  constexpr int BL = 256 * 64;
  constexpr int ABYTES = BM * 128;
  constexpr int BBYTES = 256 * 128;
  constexpr int AB2 = 2 * ABYTES;
  __shared__ _Float16 lds[2 * (AL + BL)];
  const char* ldsc = (const char*)lds;

  const int tid = threadIdx.x;
  const int lane = tid & 63;
  const int w = tid >> 6, wr = w >> 2, wc = w & 3;
  const int l15 = lane & 15, grp = lane >> 4;

  const int gx = gridDim.x;
  const int nwg = gx * gridDim.y;
  const int lid = blockIdx.y * gx + blockIdx.x;
  const int wid = (lid & 7) * (nwg >> 3) + (lid >> 3);
  const int m0 = (wid / gx) * BM, n0 = (wid % gx) * 256;

  const int m2 = (l15 >> 2) & 1, m01 = l15 & 3;
  const int chunk0 = (m2 << 2) | (grp ^ m01);
  const int aoff0 = wr * 2048 + l15 * 128 + chunk0 * 16;
  const int aoff1 = aoff0 ^ 64;
  const int boff0 = wc * 2048 + l15 * 128 + chunk0 * 16;
  const int boff1 = boff0 ^ 64;

  const int srow = tid >> 3;
  const int scs8 = ((tid & 7) ^ (srow & 7)) * 8;
  const int NK = K >> 6;

  f32x4 acc[MR][4] = {};
  half8 af[MH2][2], bf[2][2];

#define STG_A(J, MHH, KN)                                                      \
  _Pragma("unroll") for (int s = 0; s < BM / 128; ++s)                         \
      glds16(A + (size_t)(m0 + (MHH) * (BM / 2) + s * 64 + srow) * K +         \
                 (size_t)(KN)*64 + scs8,                                       \
             lds + (J)*AL + ((MHH) * (BM / 2) + s * 64) * 64 + tid * 8);
#define STG_B(J, NHH, KN)                                                      \
  _Pragma("unroll") for (int s = 0; s < 2; ++s)                                \
      glds16(Bt + (size_t)(n0 + (NHH)*128 + s * 64 + srow) * K +               \
                  (size_t)(KN)*64 + scs8,                                      \
             lds + 2 * AL + (J)*BL + ((NHH)*128 + s * 64) * 64 + tid * 8);

#define STG_ALL(J, KN)                                                         \
  STG_A(J, 0, KN) STG_B(J, 0, KN) STG_B(J, 1, KN) STG_A(J, 1, KN)

#define VM_A asm volatile("s_waitcnt vmcnt(8)" ::: "memory")
#define VM_B asm volatile("s_waitcnt vmcnt(4)" ::: "memory")
#define VM_NONE

#define PHASE(J, MHQ, NHQ, RA, RB, STGSTMT, VMSTMT)                            \
  {                                                                            \
    if constexpr (RA) {                                                        \
      _Pragma("unroll") for (int i = 0; i < MH2; ++i) {                        \
        af[i][0] = *(const half8*)(ldsc + (J)*ABYTES +                         \
                                   ((MHQ)*MH2 + i) * 4096 + aoff0);            \
        af[i][1] = *(const half8*)(ldsc + (J)*ABYTES +                         \
                                   ((MHQ)*MH2 + i) * 4096 + aoff1);            \
      }                                                                        \
    }                                                                          \
    if constexpr (RB) {                                                        \
      _Pragma("unroll") for (int n = 0; n < 2; ++n) {                          \
        bf[n][0] = *(const half8*)(ldsc + AB2 + (J)*BBYTES +                   \
                                   ((NHQ)*2 + n) * 8192 + boff0);              \
        bf[n][1] = *(const half8*)(ldsc + AB2 + (J)*BBYTES +                   \
                                   ((NHQ)*2 + n) * 8192 + boff1);              \
      }                                                                        \
    }                                                                          \
    STGSTMT;                                                                   \
    __builtin_amdgcn_s_barrier();                                              \
    asm volatile("s_waitcnt lgkmcnt(0)");                                      \
    __builtin_amdgcn_sched_barrier(0);                                         \
    __builtin_amdgcn_s_setprio(1);                                             \
    _Pragma("unroll") for (int ks = 0; ks < 2; ++ks)                           \
        _Pragma("unroll") for (int i = 0; i < MH2; ++i)                        \
            _Pragma("unroll") for (int n = 0; n < 2; ++n)                      \
                acc[(MHQ)*MH2 + i][(NHQ)*2 + n] =                              \
                    __builtin_amdgcn_mfma_f32_16x16x32_f16(                    \
                        af[i][ks], bf[n][ks], acc[(MHQ)*MH2 + i][(NHQ)*2 + n], \
                        0, 0, 0);                                              \
    __builtin_amdgcn_s_setprio(0);                                             \
    VMSTMT;                                                                    \
    __builtin_amdgcn_s_barrier();                                              \
  }

#define KTILE(J, KT)                                                           \
  {                                                                            \
    const int kn_ = ((KT) + 1 < NK) ? (KT) + 1 : (KT);                         \
    PHASE(J, 0, 0, true, true, STG_ALL(1 - (J), kn_), VM_A)                    \
    PHASE(J, 0, 1, false, true, , VM_NONE)                                     \
    PHASE(J, 1, 1, true, false, , VM_NONE)                                     \
    PHASE(J, 1, 0, false, true, , VM_B)                                        \
  }

  STG_ALL(0, 0)
  VM_B;
  __builtin_amdgcn_s_barrier();

#pragma unroll 1
  for (int kt = 0; kt < NK; kt += 2) {
    KTILE(0, kt)
    KTILE(1, kt + 1)
  }
  asm volatile("s_waitcnt vmcnt(0)" ::: "memory");
#undef KTILE
#undef PHASE
#undef VM_A
#undef VM_B
#undef VM_NONE
#undef STG_ALL
#undef STG_A
#undef STG_B

  float bcol[4];
#pragma unroll
  for (int n = 0; n < 4; ++n) bcol[n] = bias[n0 + (n * 4 + wc) * 16 + l15];
#pragma unroll
  for (int m = 0; m < MR; ++m) {
#pragma unroll
    for (int rr = 0; rr < 4; ++rr) {
      const size_t row = m0 + (m * 2 + wr) * 16 + grp * 4 + rr;
#pragma unroll
      for (int n = 0; n < 4; ++n) {
        const int col = n0 + (n * 4 + wc) * 16 + l15;
        float v = acc[m][n][rr] + bcol[n];
        const size_t idx = row * N + col;
        if (EPI == 0) {
          outh[idx] = (_Float16)v;
        } else if (EPI == 1) {
          float t2 = v + res[idx];
          outf[idx] = t2;
          outh[idx] = (_Float16)t2;
        } else if (EPI == 2) {
          float g = 0.5f * v * (1.0f + fast_erf(v * 0.70710678118654752f));
          outh[idx] = (_Float16)g;
        } else {
          outf[idx] = v + res[idx];
        }
      }
    }
  }
}

// ======== fat-phase tri-buffer GEMM: BM=256, BN=128, BK=64, 2 phases/K-tile ========
// 8 waves as 4(M) x 2(N); per-wave 64x64 (A frags rows (m*4+wr)*16, B cols (n*2+wc)*16).
// Phase = full per-wave C x one K-half: 16 MFMA, 8 ds_read_b128, 3 stage issues.
// Tri-buffer stages tile kt+2; single vmcnt(6) per K-tile (drain age 3-4 phases).
template <int EPI>
__global__ __launch_bounds__(512, 2) void k_gemmf(
    const _Float16* __restrict__ A, const _Float16* __restrict__ Bt,
    const float* __restrict__ bias, const float* __restrict__ res,
    float* __restrict__ outf, _Float16* __restrict__ outh, int M, int N, int K) {
  constexpr int AL = 256 * 64, BL = 128 * 64;
  constexpr int ABY = 32768, BBY = 16384, BBASE = 3 * ABY;
  __shared__ _Float16 lds[3 * (AL + BL)];
  const char* ldsc = (const char*)lds;

  const int tid = threadIdx.x;
  const int lane = tid & 63;
  const int w = tid >> 6, wr = w >> 1, wc = w & 1;
  const int l15 = lane & 15, grp = lane >> 4;

  const int gx = gridDim.x;
  const int nwg = gx * gridDim.y;
  const int lid = blockIdx.y * gx + blockIdx.x;
  const int wid = (lid & 7) * (nwg >> 3) + (lid >> 3);
  const int m0 = (wid / gx) * 256, n0 = (wid % gx) * 128;

  const int m2 = (l15 >> 2) & 1, m01 = l15 & 3;
  const int c0 = ((m2 << 2) | (grp ^ m01)) * 16;
  const int aoff0 = wr * 2048 + l15 * 128 + c0;
  const int aoff1 = aoff0 ^ 64;
  const int boff0 = wc * 2048 + l15 * 128 + c0;
  const int boff1 = boff0 ^ 64;

  const int srow = tid >> 3;
  const int scs8 = ((tid & 7) ^ (srow & 7)) * 8;
  const int NK = K >> 6;

  const _Float16* aG = A + (size_t)(m0 + srow) * K + scs8;
  const _Float16* bG = Bt + (size_t)(n0 + srow) * K + scs8;

  f32x4 acc[4][4] = {};

#define FSTG_A(JJ, HH, KN)                                                     \
  _Pragma("unroll") for (int s = 0; s < 2; ++s)                                \
      glds16(aG + (size_t)((HH)*128 + s * 64) * K + (size_t)(KN)*64,           \
             lds + (JJ)*AL + ((HH)*128 + s * 64) * 64 + tid * 8);
#define FSTG_B(JJ, HH, KN)                                                     \
  glds16(bG + (size_t)((HH)*64) * K + (size_t)(KN)*64,                         \
         lds + 3 * AL + (JJ)*BL + (HH)*64 * 64 + tid * 8);

#define FPHASE(PA, PB, AO, BO, STGSTMT, VMSTMT)                                \
  {                                                                            \
    half8 af_[4], bf_[4];                                                      \
    _Pragma("unroll") for (int m = 0; m < 4; ++m)                              \
        af_[m] = *(const half8*)((PA) + m * 8192 + (AO));                      \
    _Pragma("unroll") for (int n = 0; n < 4; ++n)                              \
        bf_[n] = *(const half8*)((PB) + n * 4096 + (BO));                      \
    STGSTMT;                                                                   \
    __builtin_amdgcn_s_barrier();                                              \
    asm volatile("s_waitcnt lgkmcnt(0)");                                      \
    __builtin_amdgcn_sched_barrier(0);                                         \
    __builtin_amdgcn_s_setprio(1);                                             \
    _Pragma("unroll") for (int m = 0; m < 4; ++m)                              \
        _Pragma("unroll") for (int n = 0; n < 4; ++n)                          \
            acc[m][n] = __builtin_amdgcn_mfma_f32_16x16x32_f16(                \
                af_[m], bf_[n], acc[m][n], 0, 0, 0);                           \
    __builtin_amdgcn_s_setprio(0);                                             \
    VMSTMT;                                                                    \
    __builtin_amdgcn_s_barrier();                                              \
  }

  // prologue: stage tiles 0 and 1 into bufs 0,1; drain tile 0
  FSTG_A(0, 0, 0) FSTG_A(0, 1, 0) FSTG_B(0, 0, 0) FSTG_B(0, 1, 0)
  FSTG_A(1, 0, 1) FSTG_A(1, 1, 1) FSTG_B(1, 0, 1) FSTG_B(1, 1, 1)
  asm volatile("s_waitcnt vmcnt(6)" ::: "memory");
  __builtin_amdgcn_s_barrier();

  int j = 0, j2 = 2;
#pragma unroll 1
  for (int kt = 0; kt < NK; ++kt) {
    const int kn = (kt + 2 < NK) ? kt + 2 : NK - 1;
    const char* pa = ldsc + j * ABY;
    const char* pb = ldsc + BBASE + j * BBY;
    FPHASE(pa, pb, aoff0, boff0, { FSTG_A(j2, 0, kn) FSTG_B(j2, 0, kn) }, )
    FPHASE(pa, pb, aoff1, boff1, { FSTG_A(j2, 1, kn) FSTG_B(j2, 1, kn) },
           asm volatile("s_waitcnt vmcnt(6)" ::: "memory");)
    j = (j == 2) ? 0 : j + 1;
    j2 = (j2 == 2) ? 0 : j2 + 1;
  }
  asm volatile("s_waitcnt vmcnt(0)" ::: "memory");
#undef FPHASE
#undef FSTG_A
#undef FSTG_B

  float bcol[4];
#pragma unroll
  for (int n = 0; n < 4; ++n) bcol[n] = bias[n0 + (n * 2 + wc) * 16 + l15];
#pragma unroll
  for (int m = 0; m < 4; ++m) {
#pragma unroll
    for (int rr = 0; rr < 4; ++rr) {
      const size_t row = m0 + (m * 4 + wr) * 16 + grp * 4 + rr;
#pragma unroll
      for (int n = 0; n < 4; ++n) {
        const int col = n0 + (n * 2 + wc) * 16 + l15;
        float v = acc[m][n][rr] + bcol[n];
        const size_t idx = row * N + col;
        if (EPI == 0) {
          outh[idx] = (_Float16)v;
        } else if (EPI == 1) {
          float t2 = v + res[idx];
          outf[idx] = t2;
          outh[idx] = (_Float16)t2;
        } else if (EPI == 2) {
          float g = 0.5f * v * (1.0f + fast_erf(v * 0.70710678118654752f));
          outh[idx] = (_Float16)g;
        } else {
          outf[idx] = v + res[idx];
        }
      }
    }
  }
}

// ---------------- V [s,e] (from qkv) -> Vt [bh, e, s] f16 ----------------
__global__ __launch_bounds__(256) void k_vt(const _Float16* __restrict__ qkv,
                                            _Float16* __restrict__ Vt) {
  __shared__ _Float16 t[64 * 66];
  const int tid = threadIdx.x;
  const int bh = blockIdx.y, b = bh >> 4, h = bh & 15;
  const int s0 = blockIdx.x << 6;
#pragma unroll
  for (int p = 0; p < 2; ++p) {
    int lin = p * 256 + tid;
    int s = lin >> 3, c8 = lin & 7;
    half8 v = *(const half8*)&qkv[(size_t)(b * 1024 + s0 + s) * 3072 + 2048 + h * 64 + c8 * 8];
    union { half8 h8; unsigned u[4]; } u;
    u.h8 = v;
    unsigned* d = (unsigned*)&t[s * 66 + c8 * 8];
#pragma unroll
    for (int k = 0; k < 4; ++k) d[k] = u.u[k];
  }
  __syncthreads();
#pragma unroll
  for (int p = 0; p < 2; ++p) {
    int lin = p * 256 + tid;
    int e = lin >> 3, c8 = lin & 7;
    half8 v;
#pragma unroll
    for (int j = 0; j < 8; ++j) v[j] = t[(c8 * 8 + j) * 66 + e];
    *(half8*)&Vt[(size_t)(bh * 64 + e) * 1024 + s0 + c8 * 8] = v;
  }
}

// ---------------- flash attention: 4 waves, Q-tile 64, KV-tile 128 ----------------
__global__ __launch_bounds__(256) void k_attn(const _Float16* __restrict__ qkv,
                                              const _Float16* __restrict__ Vt,
                                              _Float16* __restrict__ ctx) {
  __shared__ _Float16 Ks[128 * 64];
  __shared__ _Float16 Vs[64 * 128];
  __shared__ _Float16 Ps[4][16 * 136];
  const int tid = threadIdx.x;
  const int lane = tid & 63, w = tid >> 6;
  const int l15 = lane & 15, grp = lane >> 4;
  const int bh = blockIdx.y, b = bh >> 4, h = bh & 15;
  const int q0 = blockIdx.x << 6;
  const float CSC = 0.125f * 1.44269504088896f;

  half8 qf[2];
  {
    const _Float16* qp = qkv + (size_t)(b * 1024 + q0 + w * 16 + l15) * 3072 + h * 64 + grp * 8;
    qf[0] = *(const half8*)qp;
    qf[1] = *(const half8*)(qp + 32);
  }
  f32x4 octx[4] = {};
  float mrun = -1e30f, lrun = 0.f;

  for (int kt = 0; kt < 8; ++kt) {
    const int s0 = kt * 128;
#pragma unroll
    for (int i = 0; i < 4; ++i) {
      {
        int srow = i * 32 + (tid >> 3);
        int c8 = (tid & 7) ^ (srow & 7);
        glds16(qkv + (size_t)(b * 1024 + s0 + srow) * 3072 + 1024 + h * 64 + c8 * 8,
               Ks + w * 512 + i * 2048);
      }
      {
        int erow = i * 16 + (tid >> 4);
        int c16 = (tid & 15) ^ (erow & 7);
        glds16(Vt + (size_t)(bh * 64 + erow) * 1024 + s0 + c16 * 8,
               Vs + w * 512 + i * 2048);
      }
    }
    __syncthreads();
    f32x4 sacc[8] = {};
#pragma unroll
    for (int ks = 0; ks < 2; ++ks)
#pragma unroll
      for (int f = 0; f < 8; ++f) {
        int srow = f * 16 + l15;
        half8 kf = *(const half8*)&Ks[srow * 64 + ((ks * 32 + grp * 8) ^ ((srow & 7) * 8))];
        sacc[f] = __builtin_amdgcn_mfma_f32_16x16x32_f16(kf, qf[ks], sacc[f], 0, 0, 0);
      }
    float sv[8][4];
    float tmax = -1e30f;
#pragma unroll
    for (int f = 0; f < 8; ++f)
#pragma unroll
      for (int r = 0; r < 4; ++r) {
        float v = sacc[f][r] * CSC;
        sv[f][r] = v;
        tmax = fmaxf(tmax, v);
      }
    tmax = fmaxf(tmax, __shfl_xor(tmax, 16));
    tmax = fmaxf(tmax, __shfl_xor(tmax, 32));
    float mnew = fmaxf(mrun, tmax);
    float corr = exp2f(mrun - mnew);
    float tsum = 0.f;
#pragma unroll
    for (int f = 0; f < 8; ++f)
#pragma unroll
      for (int r = 0; r < 4; ++r) {
        float pv = exp2f(sv[f][r] - mnew);
        sv[f][r] = pv;
        tsum += pv;
      }
    tsum += __shfl_xor(tsum, 16);
    tsum += __shfl_xor(tsum, 32);
    lrun = lrun * corr + tsum;
    mrun = mnew;
#pragma unroll
    for (int r = 0; r < 4; ++r) {
      float cq = __shfl(corr, (lane & 48) + grp * 4 + r);
#pragma unroll
      for (int jf = 0; jf < 4; ++jf) octx[jf][r] *= cq;
    }
#pragma unroll
    for (int f = 0; f < 8; ++f) {
      half4 pk;
      pk[0] = (_Float16)sv[f][0]; pk[1] = (_Float16)sv[f][1];
      pk[2] = (_Float16)sv[f][2]; pk[3] = (_Float16)sv[f][3];
      *(half4*)&Ps[w][l15 * 136 + f * 16 + grp * 4] = pk;
    }
#pragma unroll
    for (int ks2 = 0; ks2 < 4; ++ks2) {
      half8 pa = *(const half8*)&Ps[w][l15 * 136 + ks2 * 32 + grp * 8];
#pragma unroll
      for (int jf = 0; jf < 4; ++jf) {
        int erow = jf * 16 + l15;
        half8 vb = *(const half8*)&Vs[erow * 128 + ((ks2 * 32 + grp * 8) ^ ((erow & 7) * 8))];
        octx[jf] = __builtin_amdgcn_mfma_f32_16x16x32_f16(pa, vb, octx[jf], 0, 0, 0);
      }
    }
    __syncthreads();
  }
#pragma unroll
  for (int r = 0; r < 4; ++r) {
    float lq = __shfl(lrun, (lane & 48) + grp * 4 + r);
    float inv = 1.0f / lq;
    const size_t row = b * 1024 + q0 + w * 16 + grp * 4 + r;
#pragma unroll
    for (int jf = 0; jf < 4; ++jf)
      ctx[row * 1024 + h * 64 + jf * 16 + l15] = (_Float16)(octx[jf][r] * inv);
  }
}

// ---------------- LayerNorm ----------------
__global__ __launch_bounds__(256) void k_ln(const float* xin, const float* __restrict__ gamma,
                                            const float* __restrict__ beta, float* out) {
  __shared__ float red[8];
  const int tid = threadIdx.x;
  const size_t row = blockIdx.x;
  f32x4 v = *(const f32x4*)&xin[row * 1024 + tid * 4];
  float s = v[0] + v[1] + v[2] + v[3];
  float s2 = v[0] * v[0] + v[1] * v[1] + v[2] * v[2] + v[3] * v[3];
#pragma unroll
  for (int o = 32; o >= 1; o >>= 1) {
    s += __shfl_xor(s, o);
    s2 += __shfl_xor(s2, o);
  }
  if ((tid & 63) == 0) { red[tid >> 6] = s; red[4 + (tid >> 6)] = s2; }
  __syncthreads();
  s = red[0] + red[1] + red[2] + red[3];
  s2 = red[4] + red[5] + red[6] + red[7];
  float mu = s * (1.0f / 1024.0f);
  float var = s2 * (1.0f / 1024.0f) - mu * mu;
  float rs = rsqrtf(var + 1e-5f);
  f32x4 g = *(const f32x4*)&gamma[tid * 4];
  f32x4 bt = *(const f32x4*)&beta[tid * 4];
  f32x4 o4;
#pragma unroll
  for (int r = 0; r < 4; ++r) o4[r] = (v[r] - mu) * rs * g[r] + bt[r];
  *(f32x4*)&out[row * 1024 + tid * 4] = o4;
}

extern "C" void kernel_launch(void* const* d_in, const int* in_sizes, int n_in,
                              void* d_out, int out_size, void* d_ws, size_t ws_size,
                              hipStream_t stream) {
  (void)in_sizes; (void)n_in; (void)out_size; (void)ws_size;
  const float* x  = (const float*)d_in[0];
  const float* Wq = (const float*)d_in[1];  const float* bq = (const float*)d_in[2];
  const float* Wk = (const float*)d_in[3];  const float* bk = (const float*)d_in[4];
  const float* Wv = (const float*)d_in[5];  const float* bv = (const float*)d_in[6];
  const float* Wo = (const float*)d_in[7];  const float* bo = (const float*)d_in[8];
  const float* W1 = (const float*)d_in[9];  const float* b1 = (const float*)d_in[10];
  const float* W2 = (const float*)d_in[11]; const float* b2 = (const float*)d_in[12];
  const float* gamma = (const float*)d_in[13];
  const float* beta  = (const float*)d_in[14];
  float* out = (float*)d_out;

  char* p = (char*)d_ws;
  _Float16* xb    = (_Float16*)p;  p += (size_t)16 << 20;   // x f16; reused as ctx
  _Float16* qkv   = (_Float16*)p;
  _Float16* hbuf  = (_Float16*)p;  p += (size_t)48 << 20;
  _Float16* Vt    = (_Float16*)p;  p += (size_t)16 << 20;
  _Float16* Wqkvt = (_Float16*)p;  p += (size_t)3072 * 1024 * 2;
  _Float16* Wot   = (_Float16*)p;  p += (size_t)1024 * 1024 * 2;
  _Float16* W1t   = (_Float16*)p;  p += (size_t)4096 * 1024 * 2;
  _Float16* W2t   = (_Float16*)p;  p += (size_t)4096 * 1024 * 2;
  float*    bqkv  = (float*)p;     p += (size_t)3072 * 4;
  float*    x1    = (float*)p;     p += (size_t)32 << 20;
  _Float16* x1b   = (_Float16*)p;  p += (size_t)16 << 20;
  _Float16* ctx   = xb;

  k_cvt<<<4096, 256, 0, stream>>>(x, xb);
  k_wt<<<dim3(32, 32), 256, 0, stream>>>(Wq, Wqkvt, 1024, 1024);
  k_wt<<<dim3(32, 32), 256, 0, stream>>>(Wk, Wqkvt + 1024 * 1024, 1024, 1024);
  k_wt<<<dim3(32, 32), 256, 0, stream>>>(Wv, Wqkvt + 2048 * 1024, 1024, 1024);
  k_wt<<<dim3(32, 32), 256, 0, stream>>>(Wo, Wot, 1024, 1024);
  k_wt<<<dim3(128, 32), 256, 0, stream>>>(W1, W1t, 1024, 4096);
  k_wt<<<dim3(32, 128), 256, 0, stream>>>(W2, W2t, 4096, 1024);
  k_biascat<<<12, 256, 0, stream>>>(bq, bk, bv, bqkv);

  // QKV: [8192,3072], fat-phase BM=256,BN=128 -> grid 24x32 = 768 blocks
  k_gemmf<0><<<dim3(24, 32), 512, 0, stream>>>(xb, Wqkvt, bqkv, nullptr, nullptr, qkv,
                                               8192, 3072, 1024);
  k_vt<<<dim3(16, 128), 256, 0, stream>>>(qkv, Vt);
  k_attn<<<dim3(16, 128), 256, 0, stream>>>(qkv, Vt, ctx);
  // x1 = x + ctx@Wo + bo : fat-phase -> 8x32 = 256 blocks
  k_gemmf<1><<<dim3(8, 32), 512, 0, stream>>>(ctx, Wot, bo, x, x1, x1b, 8192, 1024, 1024);
  // h = gelu(x1@W1 + b1) : quadrant BM=256,BN=256 -> 16x32 = 512 blocks
  k_gemm8<256, 2><<<dim3(16, 32), 512, 0, stream>>>(x1b, W1t, b1, nullptr, nullptr, hbuf,
                                                    8192, 4096, 1024);
  // x2 = x1 + h@W2 + b2 -> d_out : fat-phase, K=4096 -> 8x32 = 256 blocks
  k_gemmf<3><<<dim3(8, 32), 512, 0, stream>>>(hbuf, W2t, b2, x1, out, nullptr,
                                              8192, 1024, 4096);
  k_ln<<<8192, 256, 0, stream>>>(out, gamma, beta, out);
}

// Round 6
// 372.461 us; speedup vs baseline: 1.2651x; 1.0015x over previous
//
#include <hip/hip_runtime.h>
#include <cmath>

typedef __attribute__((ext_vector_type(8))) _Float16 half8;
typedef __attribute__((ext_vector_type(4))) _Float16 half4;
typedef __attribute__((ext_vector_type(4))) float f32x4;

__device__ __forceinline__ void glds16(const void* g, void* l) {
  __builtin_amdgcn_global_load_lds(
      (__attribute__((address_space(1))) const void*)g,
      (__attribute__((address_space(3))) void*)l, 16, 0, 0);
}

// A&S 7.1.26, |err| <= 1.5e-7
__device__ __forceinline__ float fast_erf(float x) {
  float ax = fabsf(x);
  float t = 1.0f / (1.0f + 0.3275911f * ax);
  float y = t * (0.254829592f +
            t * (-0.284496736f +
            t * (1.421413741f +
            t * (-1.453152027f + t * 1.061405429f))));
  float r = 1.0f - y * __expf(-ax * ax);
  return copysignf(r, x);
}

// ---------------- f32 -> f16 convert ----------------
__global__ __launch_bounds__(256) void k_cvt(const float* __restrict__ in,
                                             _Float16* __restrict__ out) {
  int i = (blockIdx.x * 256 + threadIdx.x) * 8;
  const f32x4* p = (const f32x4*)(in + i);
  f32x4 a = p[0], b = p[1];
  half8 h;
  h[0] = (_Float16)a[0]; h[1] = (_Float16)a[1]; h[2] = (_Float16)a[2]; h[3] = (_Float16)a[3];
  h[4] = (_Float16)b[0]; h[5] = (_Float16)b[1]; h[6] = (_Float16)b[2]; h[7] = (_Float16)b[3];
  *(half8*)(out + i) = h;
}

// ---------------- W [K,N] f32 -> Wt [N,K] f16 ----------------
__global__ __launch_bounds__(256) void k_wt(const float* __restrict__ W,
                                            _Float16* __restrict__ Wt, int K, int N) {
  __shared__ float t[32][33];
  int x = threadIdx.x & 31, y4 = (threadIdx.x >> 5) << 2;
  int n0 = blockIdx.x << 5, k0 = blockIdx.y << 5;
#pragma unroll
  for (int r = 0; r < 4; ++r) t[y4 + r][x] = W[(size_t)(k0 + y4 + r) * N + n0 + x];
  __syncthreads();
#pragma unroll
  for (int r = 0; r < 4; ++r) Wt[(size_t)(n0 + y4 + r) * K + k0 + x] = (_Float16)t[x][y4 + r];
}

__global__ void k_biascat(const float* __restrict__ a, const float* __restrict__ b,
                          const float* __restrict__ c, float* __restrict__ o) {
  int i = blockIdx.x * 256 + threadIdx.x;
  const float* s = i < 1024 ? a : (i < 2048 ? b : c);
  o[i] = s[i & 1023];
}

// ======== fat-phase tri-buffer GEMM: BM=256, BN=128, BK=64, 2 phases/K-tile ========
// 8 waves as 4(M) x 2(N); per-wave 64x64 (A frags rows (m*4+wr)*16, B cols (n*2+wc)*16).
// Phase = full per-wave C x one K-half: 16 MFMA, 8 ds_read_b128, 3 stage issues.
// Tri-buffer stages tile kt+2; single vmcnt(6) per K-tile (drain age 3-4 phases).
// EPI 0: outh=(f16)(acc+bias)
// EPI 1: outh=(f16)(acc+bias+res_f32)
// EPI 2: outh=(f16)gelu(acc+bias)
// EPI 4: outf=acc+bias+(float)res_f16
template <int EPI>
__global__ __launch_bounds__(512, 2) void k_gemmf(
    const _Float16* __restrict__ A, const _Float16* __restrict__ Bt,
    const float* __restrict__ bias, const void* __restrict__ res,
    float* __restrict__ outf, _Float16* __restrict__ outh, int M, int N, int K) {
  constexpr int AL = 256 * 64, BL = 128 * 64;
  constexpr int ABY = 32768, BBY = 16384, BBASE = 3 * ABY;
  __shared__ _Float16 lds[3 * (AL + BL)];
  const char* ldsc = (const char*)lds;

  const int tid = threadIdx.x;
  const int lane = tid & 63;
  const int w = tid >> 6, wr = w >> 1, wc = w & 1;
  const int l15 = lane & 15, grp = lane >> 4;

  const int gx = gridDim.x;
  const int nwg = gx * gridDim.y;
  const int lid = blockIdx.y * gx + blockIdx.x;
  const int wid = (lid & 7) * (nwg >> 3) + (lid >> 3);
  const int m0 = (wid / gx) * 256, n0 = (wid % gx) * 128;

  const int m2 = (l15 >> 2) & 1, m01 = l15 & 3;
  const int c0 = ((m2 << 2) | (grp ^ m01)) * 16;
  const int aoff0 = wr * 2048 + l15 * 128 + c0;
  const int aoff1 = aoff0 ^ 64;
  const int boff0 = wc * 2048 + l15 * 128 + c0;
  const int boff1 = boff0 ^ 64;

  const int srow = tid >> 3;
  const int scs8 = ((tid & 7) ^ (srow & 7)) * 8;
  const int NK = K >> 6;

  const _Float16* aG = A + (size_t)(m0 + srow) * K + scs8;
  const _Float16* bG = Bt + (size_t)(n0 + srow) * K + scs8;

  f32x4 acc[4][4] = {};

#define FSTG_A(JJ, HH, KN)                                                     \
  _Pragma("unroll") for (int s = 0; s < 2; ++s)                                \
      glds16(aG + (size_t)((HH)*128 + s * 64) * K + (size_t)(KN)*64,           \
             lds + (JJ)*AL + ((HH)*128 + s * 64) * 64 + tid * 8);
#define FSTG_B(JJ, HH, KN)                                                     \
  glds16(bG + (size_t)((HH)*64) * K + (size_t)(KN)*64,                         \
         lds + 3 * AL + (JJ)*BL + (HH)*64 * 64 + tid * 8);

#define FPHASE(PA, PB, AO, BO, STGSTMT, VMSTMT)                                \
  {                                                                            \
    half8 af_[4], bf_[4];                                                      \
    _Pragma("unroll") for (int m = 0; m < 4; ++m)                              \
        af_[m] = *(const half8*)((PA) + m * 8192 + (AO));                      \
    _Pragma("unroll") for (int n = 0; n < 4; ++n)                              \
        bf_[n] = *(const half8*)((PB) + n * 4096 + (BO));                      \
    STGSTMT;                                                                   \
    __builtin_amdgcn_s_barrier();                                              \
    asm volatile("s_waitcnt lgkmcnt(0)");                                      \
    __builtin_amdgcn_sched_barrier(0);                                         \
    __builtin_amdgcn_s_setprio(1);                                             \
    _Pragma("unroll") for (int m = 0; m < 4; ++m)                              \
        _Pragma("unroll") for (int n = 0; n < 4; ++n)                          \
            acc[m][n] = __builtin_amdgcn_mfma_f32_16x16x32_f16(                \
                af_[m], bf_[n], acc[m][n], 0, 0, 0);                           \
    __builtin_amdgcn_s_setprio(0);                                             \
    VMSTMT;                                                                    \
    __builtin_amdgcn_s_barrier();                                              \
  }

  // prologue: stage tiles 0 and 1 into bufs 0,1; drain tile 0
  FSTG_A(0, 0, 0) FSTG_A(0, 1, 0) FSTG_B(0, 0, 0) FSTG_B(0, 1, 0)
  FSTG_A(1, 0, 1) FSTG_A(1, 1, 1) FSTG_B(1, 0, 1) FSTG_B(1, 1, 1)
  asm volatile("s_waitcnt vmcnt(6)" ::: "memory");
  __builtin_amdgcn_s_barrier();

  int j = 0, j2 = 2;
#pragma unroll 1
  for (int kt = 0; kt < NK; ++kt) {
    const int kn = (kt + 2 < NK) ? kt + 2 : NK - 1;
    const char* pa = ldsc + j * ABY;
    const char* pb = ldsc + BBASE + j * BBY;
    FPHASE(pa, pb, aoff0, boff0, { FSTG_A(j2, 0, kn) FSTG_B(j2, 0, kn) }, )
    FPHASE(pa, pb, aoff1, boff1, { FSTG_A(j2, 1, kn) FSTG_B(j2, 1, kn) },
           asm volatile("s_waitcnt vmcnt(6)" ::: "memory");)
    j = (j == 2) ? 0 : j + 1;
    j2 = (j2 == 2) ? 0 : j2 + 1;
  }
  asm volatile("s_waitcnt vmcnt(0)" ::: "memory");
#undef FPHASE
#undef FSTG_A
#undef FSTG_B

  float bcol[4];
#pragma unroll
  for (int n = 0; n < 4; ++n) bcol[n] = bias[n0 + (n * 2 + wc) * 16 + l15];
#pragma unroll
  for (int m = 0; m < 4; ++m) {
#pragma unroll
    for (int rr = 0; rr < 4; ++rr) {
      const size_t row = m0 + (m * 4 + wr) * 16 + grp * 4 + rr;
#pragma unroll
      for (int n = 0; n < 4; ++n) {
        const int col = n0 + (n * 2 + wc) * 16 + l15;
        float v = acc[m][n][rr] + bcol[n];
        const size_t idx = row * N + col;
        if (EPI == 0) {
          outh[idx] = (_Float16)v;
        } else if (EPI == 1) {
          float t2 = v + ((const float*)res)[idx];
          outh[idx] = (_Float16)t2;
        } else if (EPI == 2) {
          float g = 0.5f * v * (1.0f + fast_erf(v * 0.70710678118654752f));
          outh[idx] = (_Float16)g;
        } else {
          float t2 = v + (float)((const _Float16*)res)[idx];
          outf[idx] = t2;
        }
      }
    }
  }
}

// ---------------- V [s,e] (from qkv) -> Vt [bh, e, s] f16 ----------------
__global__ __launch_bounds__(256) void k_vt(const _Float16* __restrict__ qkv,
                                            _Float16* __restrict__ Vt) {
  __shared__ _Float16 t[64 * 66];
  const int tid = threadIdx.x;
  const int bh = blockIdx.y, b = bh >> 4, h = bh & 15;
  const int s0 = blockIdx.x << 6;
#pragma unroll
  for (int p = 0; p < 2; ++p) {
    int lin = p * 256 + tid;
    int s = lin >> 3, c8 = lin & 7;
    half8 v = *(const half8*)&qkv[(size_t)(b * 1024 + s0 + s) * 3072 + 2048 + h * 64 + c8 * 8];
    union { half8 h8; unsigned u[4]; } u;
    u.h8 = v;
    unsigned* d = (unsigned*)&t[s * 66 + c8 * 8];
#pragma unroll
    for (int k = 0; k < 4; ++k) d[k] = u.u[k];
  }
  __syncthreads();
#pragma unroll
  for (int p = 0; p < 2; ++p) {
    int lin = p * 256 + tid;
    int e = lin >> 3, c8 = lin & 7;
    half8 v;
#pragma unroll
    for (int j = 0; j < 8; ++j) v[j] = t[(c8 * 8 + j) * 66 + e];
    *(half8*)&Vt[(size_t)(bh * 64 + e) * 1024 + s0 + c8 * 8] = v;
  }
}

// ---------------- flash attention: 4 waves, Q-tile 64, KV-tile 128 ----------------
__global__ __launch_bounds__(256) void k_attn(const _Float16* __restrict__ qkv,
                                              const _Float16* __restrict__ Vt,
                                              _Float16* __restrict__ ctx) {
  __shared__ _Float16 Ks[128 * 64];
  __shared__ _Float16 Vs[64 * 128];
  __shared__ _Float16 Ps[4][16 * 136];
  const int tid = threadIdx.x;
  const int lane = tid & 63, w = tid >> 6;
  const int l15 = lane & 15, grp = lane >> 4;
  const int bh = blockIdx.y, b = bh >> 4, h = bh & 15;
  const int q0 = blockIdx.x << 6;
  const float CSC = 0.125f * 1.44269504088896f;

  half8 qf[2];
  {
    const _Float16* qp = qkv + (size_t)(b * 1024 + q0 + w * 16 + l15) * 3072 + h * 64 + grp * 8;
    qf[0] = *(const half8*)qp;
    qf[1] = *(const half8*)(qp + 32);
  }
  f32x4 octx[4] = {};
  float mrun = -1e30f, lrun = 0.f;

  for (int kt = 0; kt < 8; ++kt) {
    const int s0 = kt * 128;
#pragma unroll
    for (int i = 0; i < 4; ++i) {
      {
        int srow = i * 32 + (tid >> 3);
        int c8 = (tid & 7) ^ (srow & 7);
        glds16(qkv + (size_t)(b * 1024 + s0 + srow) * 3072 + 1024 + h * 64 + c8 * 8,
               Ks + w * 512 + i * 2048);
      }
      {
        int erow = i * 16 + (tid >> 4);
        int c16 = (tid & 15) ^ (erow & 7);
        glds16(Vt + (size_t)(bh * 64 + erow) * 1024 + s0 + c16 * 8,
               Vs + w * 512 + i * 2048);
      }
    }
    __syncthreads();
    f32x4 sacc[8] = {};
#pragma unroll
    for (int ks = 0; ks < 2; ++ks)
#pragma unroll
      for (int f = 0; f < 8; ++f) {
        int srow = f * 16 + l15;
        half8 kf = *(const half8*)&Ks[srow * 64 + ((ks * 32 + grp * 8) ^ ((srow & 7) * 8))];
        sacc[f] = __builtin_amdgcn_mfma_f32_16x16x32_f16(kf, qf[ks], sacc[f], 0, 0, 0);
      }
    float sv[8][4];
    float tmax = -1e30f;
#pragma unroll
    for (int f = 0; f < 8; ++f)
#pragma unroll
      for (int r = 0; r < 4; ++r) {
        float v = sacc[f][r] * CSC;
        sv[f][r] = v;
        tmax = fmaxf(tmax, v);
      }
    tmax = fmaxf(tmax, __shfl_xor(tmax, 16));
    tmax = fmaxf(tmax, __shfl_xor(tmax, 32));
    float mnew = fmaxf(mrun, tmax);
    float corr = exp2f(mrun - mnew);
    float tsum = 0.f;
#pragma unroll
    for (int f = 0; f < 8; ++f)
#pragma unroll
      for (int r = 0; r < 4; ++r) {
        float pv = exp2f(sv[f][r] - mnew);
        sv[f][r] = pv;
        tsum += pv;
      }
    tsum += __shfl_xor(tsum, 16);
    tsum += __shfl_xor(tsum, 32);
    lrun = lrun * corr + tsum;
    mrun = mnew;
#pragma unroll
    for (int r = 0; r < 4; ++r) {
      float cq = __shfl(corr, (lane & 48) + grp * 4 + r);
#pragma unroll
      for (int jf = 0; jf < 4; ++jf) octx[jf][r] *= cq;
    }
#pragma unroll
    for (int f = 0; f < 8; ++f) {
      half4 pk;
      pk[0] = (_Float16)sv[f][0]; pk[1] = (_Float16)sv[f][1];
      pk[2] = (_Float16)sv[f][2]; pk[3] = (_Float16)sv[f][3];
      *(half4*)&Ps[w][l15 * 136 + f * 16 + grp * 4] = pk;
    }
#pragma unroll
    for (int ks2 = 0; ks2 < 4; ++ks2) {
      half8 pa = *(const half8*)&Ps[w][l15 * 136 + ks2 * 32 + grp * 8];
#pragma unroll
      for (int jf = 0; jf < 4; ++jf) {
        int erow = jf * 16 + l15;
        half8 vb = *(const half8*)&Vs[erow * 128 + ((ks2 * 32 + grp * 8) ^ ((erow & 7) * 8))];
        octx[jf] = __builtin_amdgcn_mfma_f32_16x16x32_f16(pa, vb, octx[jf], 0, 0, 0);
      }
    }
    __syncthreads();
  }
#pragma unroll
  for (int r = 0; r < 4; ++r) {
    float lq = __shfl(lrun, (lane & 48) + grp * 4 + r);
    float inv = 1.0f / lq;
    const size_t row = b * 1024 + q0 + w * 16 + grp * 4 + r;
#pragma unroll
    for (int jf = 0; jf < 4; ++jf)
      ctx[row * 1024 + h * 64 + jf * 16 + l15] = (_Float16)(octx[jf][r] * inv);
  }
}

// ---------------- LayerNorm ----------------
__global__ __launch_bounds__(256) void k_ln(const float* xin, const float* __restrict__ gamma,
                                            const float* __restrict__ beta, float* out) {
  __shared__ float red[8];
  const int tid = threadIdx.x;
  const size_t row = blockIdx.x;
  f32x4 v = *(const f32x4*)&xin[row * 1024 + tid * 4];
  float s = v[0] + v[1] + v[2] + v[3];
  float s2 = v[0] * v[0] + v[1] * v[1] + v[2] * v[2] + v[3] * v[3];
#pragma unroll
  for (int o = 32; o >= 1; o >>= 1) {
    s += __shfl_xor(s, o);
    s2 += __shfl_xor(s2, o);
  }
  if ((tid & 63) == 0) { red[tid >> 6] = s; red[4 + (tid >> 6)] = s2; }
  __syncthreads();
  s = red[0] + red[1] + red[2] + red[3];
  s2 = red[4] + red[5] + red[6] + red[7];
  float mu = s * (1.0f / 1024.0f);
  float var = s2 * (1.0f / 1024.0f) - mu * mu;
  float rs = rsqrtf(var + 1e-5f);
  f32x4 g = *(const f32x4*)&gamma[tid * 4];
  f32x4 bt = *(const f32x4*)&beta[tid * 4];
  f32x4 o4;
#pragma unroll
  for (int r = 0; r < 4; ++r) o4[r] = (v[r] - mu) * rs * g[r] + bt[r];
  *(f32x4*)&out[row * 1024 + tid * 4] = o4;
}

extern "C" void kernel_launch(void* const* d_in, const int* in_sizes, int n_in,
                              void* d_out, int out_size, void* d_ws, size_t ws_size,
                              hipStream_t stream) {
  (void)in_sizes; (void)n_in; (void)out_size; (void)ws_size;
  const float* x  = (const float*)d_in[0];
  const float* Wq = (const float*)d_in[1];  const float* bq = (const float*)d_in[2];
  const float* Wk = (const float*)d_in[3];  const float* bk = (const float*)d_in[4];
  const float* Wv = (const float*)d_in[5];  const float* bv = (const float*)d_in[6];
  const float* Wo = (const float*)d_in[7];  const float* bo = (const float*)d_in[8];
  const float* W1 = (const float*)d_in[9];  const float* b1 = (const float*)d_in[10];
  const float* W2 = (const float*)d_in[11]; const float* b2 = (const float*)d_in[12];
  const float* gamma = (const float*)d_in[13];
  const float* beta  = (const float*)d_in[14];
  float* out = (float*)d_out;

  char* p = (char*)d_ws;
  _Float16* xb    = (_Float16*)p;  p += (size_t)16 << 20;   // x f16; reused as ctx
  _Float16* qkv   = (_Float16*)p;
  _Float16* hbuf  = (_Float16*)p;  p += (size_t)48 << 20;
  _Float16* Vt    = (_Float16*)p;  p += (size_t)16 << 20;
  _Float16* Wqkvt = (_Float16*)p;  p += (size_t)3072 * 1024 * 2;
  _Float16* Wot   = (_Float16*)p;  p += (size_t)1024 * 1024 * 2;
  _Float16* W1t   = (_Float16*)p;  p += (size_t)4096 * 1024 * 2;
  _Float16* W2t   = (_Float16*)p;  p += (size_t)4096 * 1024 * 2;
  float*    bqkv  = (float*)p;     p += (size_t)3072 * 4;
  _Float16* x1b   = (_Float16*)p;  p += (size_t)16 << 20;
  _Float16* ctx   = xb;

  k_cvt<<<4096, 256, 0, stream>>>(x, xb);
  k_wt<<<dim3(32, 32), 256, 0, stream>>>(Wq, Wqkvt, 1024, 1024);
  k_wt<<<dim3(32, 32), 256, 0, stream>>>(Wk, Wqkvt + 1024 * 1024, 1024, 1024);
  k_wt<<<dim3(32, 32), 256, 0, stream>>>(Wv, Wqkvt + 2048 * 1024, 1024, 1024);
  k_wt<<<dim3(32, 32), 256, 0, stream>>>(Wo, Wot, 1024, 1024);
  k_wt<<<dim3(128, 32), 256, 0, stream>>>(W1, W1t, 1024, 4096);
  k_wt<<<dim3(32, 128), 256, 0, stream>>>(W2, W2t, 4096, 1024);
  k_biascat<<<12, 256, 0, stream>>>(bq, bk, bv, bqkv);

  // QKV: [8192,3072], fat-phase BM=256,BN=128 -> grid 24x32 = 768 blocks
  k_gemmf<0><<<dim3(24, 32), 512, 0, stream>>>(xb, Wqkvt, bqkv, nullptr, nullptr, qkv,
                                               8192, 3072, 1024);
  k_vt<<<dim3(16, 128), 256, 0, stream>>>(qkv, Vt);
  k_attn<<<dim3(16, 128), 256, 0, stream>>>(qkv, Vt, ctx);
  // x1b = (f16)(x + ctx@Wo + bo) : fat-phase -> 8x32 = 256 blocks
  k_gemmf<1><<<dim3(8, 32), 512, 0, stream>>>(ctx, Wot, bo, x, nullptr, x1b,
                                              8192, 1024, 1024);
  // h = gelu(x1b@W1 + b1) : fat-phase -> 32x32 = 1024 blocks (4 exact rounds)
  k_gemmf<2><<<dim3(32, 32), 512, 0, stream>>>(x1b, W1t, b1, nullptr, nullptr, hbuf,
                                               8192, 4096, 1024);
  // out = x1b + h@W2 + b2 (f32) : fat-phase, K=4096 -> 8x32 = 256 blocks
  k_gemmf<4><<<dim3(8, 32), 512, 0, stream>>>(hbuf, W2t, b2, x1b, out, nullptr,
                                              8192, 1024, 4096);
  k_ln<<<8192, 256, 0, stream>>>(out, gamma, beta, out);
}

// Round 7
// 360.304 us; speedup vs baseline: 1.3078x; 1.0337x over previous
//
#include <hip/hip_runtime.h>
#include <cmath>

typedef __attribute__((ext_vector_type(8))) _Float16 half8;
typedef __attribute__((ext_vector_type(4))) _Float16 half4;
typedef __attribute__((ext_vector_type(4))) float f32x4;

__device__ __forceinline__ void glds16(const void* g, void* l) {
  __builtin_amdgcn_global_load_lds(
      (__attribute__((address_space(1))) const void*)g,
      (__attribute__((address_space(3))) void*)l, 16, 0, 0);
}

// A&S 7.1.26, |err| <= 1.5e-7
__device__ __forceinline__ float fast_erf(float x) {
  float ax = fabsf(x);
  float t = 1.0f / (1.0f + 0.3275911f * ax);
  float y = t * (0.254829592f +
            t * (-0.284496736f +
            t * (1.421413741f +
            t * (-1.453152027f + t * 1.061405429f))));
  float r = 1.0f - y * __expf(-ax * ax);
  return copysignf(r, x);
}

// ---------------- f32 -> f16 convert ----------------
__global__ __launch_bounds__(256) void k_cvt(const float* __restrict__ in,
                                             _Float16* __restrict__ out) {
  int i = (blockIdx.x * 256 + threadIdx.x) * 8;
  const f32x4* p = (const f32x4*)(in + i);
  f32x4 a = p[0], b = p[1];
  half8 h;
  h[0] = (_Float16)a[0]; h[1] = (_Float16)a[1]; h[2] = (_Float16)a[2]; h[3] = (_Float16)a[3];
  h[4] = (_Float16)b[0]; h[5] = (_Float16)b[1]; h[6] = (_Float16)b[2]; h[7] = (_Float16)b[3];
  *(half8*)(out + i) = h;
}

// ---------------- W [K,N] f32 -> Wt [N,K] f16 ----------------
__global__ __launch_bounds__(256) void k_wt(const float* __restrict__ W,
                                            _Float16* __restrict__ Wt, int K, int N) {
  __shared__ float t[32][33];
  int x = threadIdx.x & 31, y4 = (threadIdx.x >> 5) << 2;
  int n0 = blockIdx.x << 5, k0 = blockIdx.y << 5;
#pragma unroll
  for (int r = 0; r < 4; ++r) t[y4 + r][x] = W[(size_t)(k0 + y4 + r) * N + n0 + x];
  __syncthreads();
#pragma unroll
  for (int r = 0; r < 4; ++r) Wt[(size_t)(n0 + y4 + r) * K + k0 + x] = (_Float16)t[x][y4 + r];
}

__global__ void k_biascat(const float* __restrict__ a, const float* __restrict__ b,
                          const float* __restrict__ c, float* __restrict__ o) {
  int i = blockIdx.x * 256 + threadIdx.x;
  const float* s = i < 1024 ? a : (i < 2048 ? b : c);
  o[i] = s[i & 1023];
}

// ======== quadrant 8-phase GEMM: BM=256,BN=256, BK=64, dbuf, SPREAD staging ========
// 8 waves (2M x 4N), per-wave 128x64. Quadrant walk (M0N0)(M0N1)(M1N1)(M1N0).
// Staging 1 half-tile/phase: ph1 A0(t+1), ph2 A1(t+1), ph3 B0(t+1), ph4 B1(t+2)
// (B1 region of the CURRENT buffer frees after ph3 -> extra-deep issue legal).
// Single vmcnt(2) at ph4-end: drains all of tile t+1, keeps B1(t+2) in flight.
template <int BM, int EPI>
__global__ __launch_bounds__(512, 2) void k_gemm8(
    const _Float16* __restrict__ A, const _Float16* __restrict__ Bt,
    const float* __restrict__ bias, const float* __restrict__ res,
    float* __restrict__ outf, _Float16* __restrict__ outh, int M, int N, int K) {
  constexpr int MR = BM / 32;
  constexpr int MH2 = MR / 2;
  constexpr int AL = BM * 64;
  constexpr int BL = 256 * 64;
  constexpr int ABYTES = BM * 128;
  constexpr int BBYTES = 256 * 128;
  constexpr int AB2 = 2 * ABYTES;
  __shared__ _Float16 lds[2 * (AL + BL)];
  const char* ldsc = (const char*)lds;

  const int tid = threadIdx.x;
  const int lane = tid & 63;
  const int w = tid >> 6, wr = w >> 2, wc = w & 3;
  const int l15 = lane & 15, grp = lane >> 4;

  const int gx = gridDim.x;
  const int nwg = gx * gridDim.y;
  const int lid = blockIdx.y * gx + blockIdx.x;
  const int wid = (lid & 7) * (nwg >> 3) + (lid >> 3);
  const int m0 = (wid / gx) * BM, n0 = (wid % gx) * 256;

  const int m2 = (l15 >> 2) & 1, m01 = l15 & 3;
  const int chunk0 = (m2 << 2) | (grp ^ m01);
  const int aoff0 = wr * 2048 + l15 * 128 + chunk0 * 16;
  const int aoff1 = aoff0 ^ 64;
  const int boff0 = wc * 2048 + l15 * 128 + chunk0 * 16;
  const int boff1 = boff0 ^ 64;

  const int srow = tid >> 3;
  const int scs8 = ((tid & 7) ^ (srow & 7)) * 8;
  const int NK = K >> 6;

  f32x4 acc[MR][4] = {};
  half8 af[MH2][2], bf[2][2];

#define STG_A(J, MHH, KN)                                                      \
  _Pragma("unroll") for (int s = 0; s < BM / 128; ++s)                         \
      glds16(A + (size_t)(m0 + (MHH) * (BM / 2) + s * 64 + srow) * K +         \
                 (size_t)(KN)*64 + scs8,                                       \
             lds + (J)*AL + ((MHH) * (BM / 2) + s * 64) * 64 + tid * 8);
#define STG_B(J, NHH, KN)                                                      \
  _Pragma("unroll") for (int s = 0; s < 2; ++s)                                \
      glds16(Bt + (size_t)(n0 + (NHH)*128 + s * 64 + srow) * K +               \
                  (size_t)(KN)*64 + scs8,                                      \
             lds + 2 * AL + (J)*BL + ((NHH)*128 + s * 64) * 64 + tid * 8);

#define VM_C asm volatile("s_waitcnt vmcnt(2)" ::: "memory")
#define VM_NONE

#define PHASE(J, MHQ, NHQ, RA, RB, STGSTMT, VMSTMT)                            \
  {                                                                            \
    if constexpr (RA) {                                                        \
      _Pragma("unroll") for (int i = 0; i < MH2; ++i) {                        \
        af[i][0] = *(const half8*)(ldsc + (J)*ABYTES +                         \
                                   ((MHQ)*MH2 + i) * 4096 + aoff0);            \
        af[i][1] = *(const half8*)(ldsc + (J)*ABYTES +                         \
                                   ((MHQ)*MH2 + i) * 4096 + aoff1);            \
      }                                                                        \
    }                                                                          \
    if constexpr (RB) {                                                        \
      _Pragma("unroll") for (int n = 0; n < 2; ++n) {                          \
        bf[n][0] = *(const half8*)(ldsc + AB2 + (J)*BBYTES +                   \
                                   ((NHQ)*2 + n) * 8192 + boff0);              \
        bf[n][1] = *(const half8*)(ldsc + AB2 + (J)*BBYTES +                   \
                                   ((NHQ)*2 + n) * 8192 + boff1);              \
      }                                                                        \
    }                                                                          \
    STGSTMT;                                                                   \
    __builtin_amdgcn_s_barrier();                                              \
    asm volatile("s_waitcnt lgkmcnt(0)");                                      \
    __builtin_amdgcn_sched_barrier(0);                                         \
    __builtin_amdgcn_s_setprio(1);                                             \
    _Pragma("unroll") for (int ks = 0; ks < 2; ++ks)                           \
        _Pragma("unroll") for (int i = 0; i < MH2; ++i)                        \
            _Pragma("unroll") for (int n = 0; n < 2; ++n)                      \
                acc[(MHQ)*MH2 + i][(NHQ)*2 + n] =                              \
                    __builtin_amdgcn_mfma_f32_16x16x32_f16(                    \
                        af[i][ks], bf[n][ks], acc[(MHQ)*MH2 + i][(NHQ)*2 + n], \
                        0, 0, 0);                                              \
    __builtin_amdgcn_s_setprio(0);                                             \
    VMSTMT;                                                                    \
    __builtin_amdgcn_s_barrier();                                              \
  }

#define KTILE(J, KT)                                                           \
  {                                                                            \
    const int kn_ = ((KT) + 1 < NK) ? (KT) + 1 : NK - 1;                       \
    const int kn2_ = ((KT) + 2 < NK) ? (KT) + 2 : NK - 1;                      \
    PHASE(J, 0, 0, true, true, STG_A(1 - (J), 0, kn_), VM_NONE)                \
    PHASE(J, 0, 1, false, true, STG_A(1 - (J), 1, kn_), VM_NONE)               \
    PHASE(J, 1, 1, true, false, STG_B(1 - (J), 0, kn_), VM_NONE)               \
    PHASE(J, 1, 0, false, true, STG_B(J, 1, kn2_), VM_C)                       \
  }

  // prologue: tile0 fully + B1 of tile1; drain tile0, keep B1(t1) in flight
  STG_A(0, 0, 0) STG_A(0, 1, 0) STG_B(0, 0, 0) STG_B(0, 1, 0)
  STG_B(1, 1, 1)
  VM_C;
  __builtin_amdgcn_s_barrier();

#pragma unroll 1
  for (int kt = 0; kt < NK; kt += 2) {
    KTILE(0, kt)
    KTILE(1, kt + 1)
  }
  asm volatile("s_waitcnt vmcnt(0)" ::: "memory");
#undef KTILE
#undef PHASE
#undef VM_C
#undef VM_NONE
#undef STG_A
#undef STG_B

  float bcol[4];
#pragma unroll
  for (int n = 0; n < 4; ++n) bcol[n] = bias[n0 + (n * 4 + wc) * 16 + l15];
#pragma unroll
  for (int m = 0; m < MR; ++m) {
#pragma unroll
    for (int rr = 0; rr < 4; ++rr) {
      const size_t row = m0 + (m * 2 + wr) * 16 + grp * 4 + rr;
#pragma unroll
      for (int n = 0; n < 4; ++n) {
        const int col = n0 + (n * 4 + wc) * 16 + l15;
        float v = acc[m][n][rr] + bcol[n];
        const size_t idx = row * N + col;
        if (EPI == 0) {
          outh[idx] = (_Float16)v;
        } else if (EPI == 1) {
          float t2 = v + res[idx];
          outf[idx] = t2;
          outh[idx] = (_Float16)t2;
        } else if (EPI == 2) {
          float g = 0.5f * v * (1.0f + fast_erf(v * 0.70710678118654752f));
          outh[idx] = (_Float16)g;
        } else {
          outf[idx] = v + res[idx];
        }
      }
    }
  }
}

// ======== fat-phase tri-buffer GEMM: BM=256, BN=128, BK=64, 2 phases/K-tile ========
// EPI 0: outh=(f16)(acc+bias); 1: outh=(f16)(acc+bias+res_f32);
// EPI 2: outh=(f16)gelu(acc+bias); 4: outf=acc+bias+(float)res_f16
template <int EPI>
__global__ __launch_bounds__(512, 2) void k_gemmf(
    const _Float16* __restrict__ A, const _Float16* __restrict__ Bt,
    const float* __restrict__ bias, const void* __restrict__ res,
    float* __restrict__ outf, _Float16* __restrict__ outh, int M, int N, int K) {
  constexpr int AL = 256 * 64, BL = 128 * 64;
  constexpr int ABY = 32768, BBY = 16384, BBASE = 3 * ABY;
  __shared__ _Float16 lds[3 * (AL + BL)];
  const char* ldsc = (const char*)lds;

  const int tid = threadIdx.x;
  const int lane = tid & 63;
  const int w = tid >> 6, wr = w >> 1, wc = w & 1;
  const int l15 = lane & 15, grp = lane >> 4;

  const int gx = gridDim.x;
  const int nwg = gx * gridDim.y;
  const int lid = blockIdx.y * gx + blockIdx.x;
  const int wid = (lid & 7) * (nwg >> 3) + (lid >> 3);
  const int m0 = (wid / gx) * 256, n0 = (wid % gx) * 128;

  const int m2 = (l15 >> 2) & 1, m01 = l15 & 3;
  const int c0 = ((m2 << 2) | (grp ^ m01)) * 16;
  const int aoff0 = wr * 2048 + l15 * 128 + c0;
  const int aoff1 = aoff0 ^ 64;
  const int boff0 = wc * 2048 + l15 * 128 + c0;
  const int boff1 = boff0 ^ 64;

  const int srow = tid >> 3;
  const int scs8 = ((tid & 7) ^ (srow & 7)) * 8;
  const int NK = K >> 6;

  const _Float16* aG = A + (size_t)(m0 + srow) * K + scs8;
  const _Float16* bG = Bt + (size_t)(n0 + srow) * K + scs8;

  f32x4 acc[4][4] = {};

#define FSTG_A(JJ, HH, KN)                                                     \
  _Pragma("unroll") for (int s = 0; s < 2; ++s)                                \
      glds16(aG + (size_t)((HH)*128 + s * 64) * K + (size_t)(KN)*64,           \
             lds + (JJ)*AL + ((HH)*128 + s * 64) * 64 + tid * 8);
#define FSTG_B(JJ, HH, KN)                                                     \
  glds16(bG + (size_t)((HH)*64) * K + (size_t)(KN)*64,                         \
         lds + 3 * AL + (JJ)*BL + (HH)*64 * 64 + tid * 8);

#define FPHASE(PA, PB, AO, BO, STGSTMT, VMSTMT)                                \
  {                                                                            \
    half8 af_[4], bf_[4];                                                      \
    _Pragma("unroll") for (int m = 0; m < 4; ++m)                              \
        af_[m] = *(const half8*)((PA) + m * 8192 + (AO));                      \
    _Pragma("unroll") for (int n = 0; n < 4; ++n)                              \
        bf_[n] = *(const half8*)((PB) + n * 4096 + (BO));                      \
    STGSTMT;                                                                   \
    __builtin_amdgcn_s_barrier();                                              \
    asm volatile("s_waitcnt lgkmcnt(0)");                                      \
    __builtin_amdgcn_sched_barrier(0);                                         \
    __builtin_amdgcn_s_setprio(1);                                             \
    _Pragma("unroll") for (int m = 0; m < 4; ++m)                              \
        _Pragma("unroll") for (int n = 0; n < 4; ++n)                          \
            acc[m][n] = __builtin_amdgcn_mfma_f32_16x16x32_f16(                \
                af_[m], bf_[n], acc[m][n], 0, 0, 0);                           \
    __builtin_amdgcn_s_setprio(0);                                             \
    VMSTMT;                                                                    \
    __builtin_amdgcn_s_barrier();                                              \
  }

  FSTG_A(0, 0, 0) FSTG_A(0, 1, 0) FSTG_B(0, 0, 0) FSTG_B(0, 1, 0)
  FSTG_A(1, 0, 1) FSTG_A(1, 1, 1) FSTG_B(1, 0, 1) FSTG_B(1, 1, 1)
  asm volatile("s_waitcnt vmcnt(6)" ::: "memory");
  __builtin_amdgcn_s_barrier();

  int j = 0, j2 = 2;
#pragma unroll 1
  for (int kt = 0; kt < NK; ++kt) {
    const int kn = (kt + 2 < NK) ? kt + 2 : NK - 1;
    const char* pa = ldsc + j * ABY;
    const char* pb = ldsc + BBASE + j * BBY;
    FPHASE(pa, pb, aoff0, boff0, { FSTG_A(j2, 0, kn) FSTG_B(j2, 0, kn) }, )
    FPHASE(pa, pb, aoff1, boff1, { FSTG_A(j2, 1, kn) FSTG_B(j2, 1, kn) },
           asm volatile("s_waitcnt vmcnt(6)" ::: "memory");)
    j = (j == 2) ? 0 : j + 1;
    j2 = (j2 == 2) ? 0 : j2 + 1;
  }
  asm volatile("s_waitcnt vmcnt(0)" ::: "memory");
#undef FPHASE
#undef FSTG_A
#undef FSTG_B

  float bcol[4];
#pragma unroll
  for (int n = 0; n < 4; ++n) bcol[n] = bias[n0 + (n * 2 + wc) * 16 + l15];
#pragma unroll
  for (int m = 0; m < 4; ++m) {
#pragma unroll
    for (int rr = 0; rr < 4; ++rr) {
      const size_t row = m0 + (m * 4 + wr) * 16 + grp * 4 + rr;
#pragma unroll
      for (int n = 0; n < 4; ++n) {
        const int col = n0 + (n * 2 + wc) * 16 + l15;
        float v = acc[m][n][rr] + bcol[n];
        const size_t idx = row * N + col;
        if (EPI == 0) {
          outh[idx] = (_Float16)v;
        } else if (EPI == 1) {
          float t2 = v + ((const float*)res)[idx];
          outh[idx] = (_Float16)t2;
        } else if (EPI == 2) {
          float g = 0.5f * v * (1.0f + fast_erf(v * 0.70710678118654752f));
          outh[idx] = (_Float16)g;
        } else {
          float t2 = v + (float)((const _Float16*)res)[idx];
          outf[idx] = t2;
        }
      }
    }
  }
}

// ---------------- V [s,e] (from qkv) -> Vt [bh, e, s] f16 ----------------
__global__ __launch_bounds__(256) void k_vt(const _Float16* __restrict__ qkv,
                                            _Float16* __restrict__ Vt) {
  __shared__ _Float16 t[64 * 66];
  const int tid = threadIdx.x;
  const int bh = blockIdx.y, b = bh >> 4, h = bh & 15;
  const int s0 = blockIdx.x << 6;
#pragma unroll
  for (int p = 0; p < 2; ++p) {
    int lin = p * 256 + tid;
    int s = lin >> 3, c8 = lin & 7;
    half8 v = *(const half8*)&qkv[(size_t)(b * 1024 + s0 + s) * 3072 + 2048 + h * 64 + c8 * 8];
    union { half8 h8; unsigned u[4]; } u;
    u.h8 = v;
    unsigned* d = (unsigned*)&t[s * 66 + c8 * 8];
#pragma unroll
    for (int k = 0; k < 4; ++k) d[k] = u.u[k];
  }
  __syncthreads();
#pragma unroll
  for (int p = 0; p < 2; ++p) {
    int lin = p * 256 + tid;
    int e = lin >> 3, c8 = lin & 7;
    half8 v;
#pragma unroll
    for (int j = 0; j < 8; ++j) v[j] = t[(c8 * 8 + j) * 66 + e];
    *(half8*)&Vt[(size_t)(bh * 64 + e) * 1024 + s0 + c8 * 8] = v;
  }
}

// ---------------- flash attention: 4 waves, Q-tile 64, KV-tile 128 ----------------
__global__ __launch_bounds__(256) void k_attn(const _Float16* __restrict__ qkv,
                                              const _Float16* __restrict__ Vt,
                                              _Float16* __restrict__ ctx) {
  __shared__ _Float16 Ks[128 * 64];
  __shared__ _Float16 Vs[64 * 128];
  __shared__ _Float16 Ps[4][16 * 136];
  const int tid = threadIdx.x;
  const int lane = tid & 63, w = tid >> 6;
  const int l15 = lane & 15, grp = lane >> 4;
  const int bh = blockIdx.y, b = bh >> 4, h = bh & 15;
  const int q0 = blockIdx.x << 6;
  const float CSC = 0.125f * 1.44269504088896f;

  half8 qf[2];
  {
    const _Float16* qp = qkv + (size_t)(b * 1024 + q0 + w * 16 + l15) * 3072 + h * 64 + grp * 8;
    qf[0] = *(const half8*)qp;
    qf[1] = *(const half8*)(qp + 32);
  }
  f32x4 octx[4] = {};
  float mrun = -1e30f, lrun = 0.f;

  for (int kt = 0; kt < 8; ++kt) {
    const int s0 = kt * 128;
#pragma unroll
    for (int i = 0; i < 4; ++i) {
      {
        int srow = i * 32 + (tid >> 3);
        int c8 = (tid & 7) ^ (srow & 7);
        glds16(qkv + (size_t)(b * 1024 + s0 + srow) * 3072 + 1024 + h * 64 + c8 * 8,
               Ks + w * 512 + i * 2048);
      }
      {
        int erow = i * 16 + (tid >> 4);
        int c16 = (tid & 15) ^ (erow & 7);
        glds16(Vt + (size_t)(bh * 64 + erow) * 1024 + s0 + c16 * 8,
               Vs + w * 512 + i * 2048);
      }
    }
    __syncthreads();
    f32x4 sacc[8] = {};
#pragma unroll
    for (int ks = 0; ks < 2; ++ks)
#pragma unroll
      for (int f = 0; f < 8; ++f) {
        int srow = f * 16 + l15;
        half8 kf = *(const half8*)&Ks[srow * 64 + ((ks * 32 + grp * 8) ^ ((srow & 7) * 8))];
        sacc[f] = __builtin_amdgcn_mfma_f32_16x16x32_f16(kf, qf[ks], sacc[f], 0, 0, 0);
      }
    float sv[8][4];
    float tmax = -1e30f;
#pragma unroll
    for (int f = 0; f < 8; ++f)
#pragma unroll
      for (int r = 0; r < 4; ++r) {
        float v = sacc[f][r] * CSC;
        sv[f][r] = v;
        tmax = fmaxf(tmax, v);
      }
    tmax = fmaxf(tmax, __shfl_xor(tmax, 16));
    tmax = fmaxf(tmax, __shfl_xor(tmax, 32));
    float mnew = fmaxf(mrun, tmax);
    float corr = exp2f(mrun - mnew);
    float tsum = 0.f;
#pragma unroll
    for (int f = 0; f < 8; ++f)
#pragma unroll
      for (int r = 0; r < 4; ++r) {
        float pv = exp2f(sv[f][r] - mnew);
        sv[f][r] = pv;
        tsum += pv;
      }
    tsum += __shfl_xor(tsum, 16);
    tsum += __shfl_xor(tsum, 32);
    lrun = lrun * corr + tsum;
    mrun = mnew;
#pragma unroll
    for (int r = 0; r < 4; ++r) {
      float cq = __shfl(corr, (lane & 48) + grp * 4 + r);
#pragma unroll
      for (int jf = 0; jf < 4; ++jf) octx[jf][r] *= cq;
    }
#pragma unroll
    for (int f = 0; f < 8; ++f) {
      half4 pk;
      pk[0] = (_Float16)sv[f][0]; pk[1] = (_Float16)sv[f][1];
      pk[2] = (_Float16)sv[f][2]; pk[3] = (_Float16)sv[f][3];
      *(half4*)&Ps[w][l15 * 136 + f * 16 + grp * 4] = pk;
    }
#pragma unroll
    for (int ks2 = 0; ks2 < 4; ++ks2) {
      half8 pa = *(const half8*)&Ps[w][l15 * 136 + ks2 * 32 + grp * 8];
#pragma unroll
      for (int jf = 0; jf < 4; ++jf) {
        int erow = jf * 16 + l15;
        half8 vb = *(const half8*)&Vs[erow * 128 + ((ks2 * 32 + grp * 8) ^ ((erow & 7) * 8))];
        octx[jf] = __builtin_amdgcn_mfma_f32_16x16x32_f16(pa, vb, octx[jf], 0, 0, 0);
      }
    }
    __syncthreads();
  }
#pragma unroll
  for (int r = 0; r < 4; ++r) {
    float lq = __shfl(lrun, (lane & 48) + grp * 4 + r);
    float inv = 1.0f / lq;
    const size_t row = b * 1024 + q0 + w * 16 + grp * 4 + r;
#pragma unroll
    for (int jf = 0; jf < 4; ++jf)
      ctx[row * 1024 + h * 64 + jf * 16 + l15] = (_Float16)(octx[jf][r] * inv);
  }
}

// ---------------- LayerNorm ----------------
__global__ __launch_bounds__(256) void k_ln(const float* xin, const float* __restrict__ gamma,
                                            const float* __restrict__ beta, float* out) {
  __shared__ float red[8];
  const int tid = threadIdx.x;
  const size_t row = blockIdx.x;
  f32x4 v = *(const f32x4*)&xin[row * 1024 + tid * 4];
  float s = v[0] + v[1] + v[2] + v[3];
  float s2 = v[0] * v[0] + v[1] * v[1] + v[2] * v[2] + v[3] * v[3];
#pragma unroll
  for (int o = 32; o >= 1; o >>= 1) {
    s += __shfl_xor(s, o);
    s2 += __shfl_xor(s2, o);
  }
  if ((tid & 63) == 0) { red[tid >> 6] = s; red[4 + (tid >> 6)] = s2; }
  __syncthreads();
  s = red[0] + red[1] + red[2] + red[3];
  s2 = red[4] + red[5] + red[6] + red[7];
  float mu = s * (1.0f / 1024.0f);
  float var = s2 * (1.0f / 1024.0f) - mu * mu;
  float rs = rsqrtf(var + 1e-5f);
  f32x4 g = *(const f32x4*)&gamma[tid * 4];
  f32x4 bt = *(const f32x4*)&beta[tid * 4];
  f32x4 o4;
#pragma unroll
  for (int r = 0; r < 4; ++r) o4[r] = (v[r] - mu) * rs * g[r] + bt[r];
  *(f32x4*)&out[row * 1024 + tid * 4] = o4;
}

extern "C" void kernel_launch(void* const* d_in, const int* in_sizes, int n_in,
                              void* d_out, int out_size, void* d_ws, size_t ws_size,
                              hipStream_t stream) {
  (void)in_sizes; (void)n_in; (void)out_size; (void)ws_size;
  const float* x  = (const float*)d_in[0];
  const float* Wq = (const float*)d_in[1];  const float* bq = (const float*)d_in[2];
  const float* Wk = (const float*)d_in[3];  const float* bk = (const float*)d_in[4];
  const float* Wv = (const float*)d_in[5];  const float* bv = (const float*)d_in[6];
  const float* Wo = (const float*)d_in[7];  const float* bo = (const float*)d_in[8];
  const float* W1 = (const float*)d_in[9];  const float* b1 = (const float*)d_in[10];
  const float* W2 = (const float*)d_in[11]; const float* b2 = (const float*)d_in[12];
  const float* gamma = (const float*)d_in[13];
  const float* beta  = (const float*)d_in[14];
  float* out = (float*)d_out;

  char* p = (char*)d_ws;
  _Float16* xb    = (_Float16*)p;  p += (size_t)16 << 20;   // x f16; reused as ctx
  _Float16* qkv   = (_Float16*)p;
  _Float16* hbuf  = (_Float16*)p;  p += (size_t)48 << 20;
  _Float16* Vt    = (_Float16*)p;  p += (size_t)16 << 20;
  _Float16* Wqkvt = (_Float16*)p;  p += (size_t)3072 * 1024 * 2;
  _Float16* Wot   = (_Float16*)p;  p += (size_t)1024 * 1024 * 2;
  _Float16* W1t   = (_Float16*)p;  p += (size_t)4096 * 1024 * 2;
  _Float16* W2t   = (_Float16*)p;  p += (size_t)4096 * 1024 * 2;
  float*    bqkv  = (float*)p;     p += (size_t)3072 * 4;
  _Float16* x1b   = (_Float16*)p;  p += (size_t)16 << 20;
  _Float16* ctx   = xb;

  k_cvt<<<4096, 256, 0, stream>>>(x, xb);
  k_wt<<<dim3(32, 32), 256, 0, stream>>>(Wq, Wqkvt, 1024, 1024);
  k_wt<<<dim3(32, 32), 256, 0, stream>>>(Wk, Wqkvt + 1024 * 1024, 1024, 1024);
  k_wt<<<dim3(32, 32), 256, 0, stream>>>(Wv, Wqkvt + 2048 * 1024, 1024, 1024);
  k_wt<<<dim3(32, 32), 256, 0, stream>>>(Wo, Wot, 1024, 1024);
  k_wt<<<dim3(128, 32), 256, 0, stream>>>(W1, W1t, 1024, 4096);
  k_wt<<<dim3(32, 128), 256, 0, stream>>>(W2, W2t, 4096, 1024);
  k_biascat<<<12, 256, 0, stream>>>(bq, bk, bv, bqkv);

  // QKV: fat128 BM=256,BN=128 -> 24x32 = 768 blocks (control, unchanged)
  k_gemmf<0><<<dim3(24, 32), 512, 0, stream>>>(xb, Wqkvt, bqkv, nullptr, nullptr, qkv,
                                               8192, 3072, 1024);
  k_vt<<<dim3(16, 128), 256, 0, stream>>>(qkv, Vt);
  k_attn<<<dim3(16, 128), 256, 0, stream>>>(qkv, Vt, ctx);
  // x1b = (f16)(x + ctx@Wo + bo) : fat128 -> 8x32 = 256 blocks (control)
  k_gemmf<1><<<dim3(8, 32), 512, 0, stream>>>(ctx, Wot, bo, x, nullptr, x1b,
                                              8192, 1024, 1024);
  // h = gelu(x1b@W1 + b1) : quadrant + SPREAD staging -> 16x32 = 512 blocks
  k_gemm8<256, 2><<<dim3(16, 32), 512, 0, stream>>>(x1b, W1t, b1, nullptr, nullptr, hbuf,
                                                    8192, 4096, 1024);
  // out = x1b + h@W2 + b2 (f32) : fat128, K=4096 -> 8x32 = 256 blocks (control)
  k_gemmf<4><<<dim3(8, 32), 512, 0, stream>>>(hbuf, W2t, b2, x1b, out, nullptr,
                                              8192, 1024, 4096);
  k_ln<<<8192, 256, 0, stream>>>(out, gamma, beta, out);
}